// Round 11
// baseline (306.851 us; speedup 1.0000x reference)
//
#include <hip/hip_runtime.h>
#include <hip/hip_bf16.h>

#define NB 32
#define CH 64
#define TF 300
#define VJ 25
#define NSUB 3
#define ICB 16
#define KW 9
#define EPSB 1e-5f

#define TVsz (TF*VJ)          // 7500
#define CTVsz (CH*TF*VJ)      // 480000
#define TOTAL (NB*CTVsz)      // 15360000
#define PCCOUNT (NB*TF*VJ)    // 240000

#define ATC 32                // t per attention chunk
#define ATCN 10               // ceil(300/32)

typedef __attribute__((ext_vector_type(8))) short s16x8;
typedef __attribute__((ext_vector_type(4))) float f32x4;

__device__ __forceinline__ unsigned short f2bf(float v) {
    __hip_bfloat16 h = __float2bfloat16(v);
    return *(unsigned short*)&h;
}
__device__ __forceinline__ float bf2f(unsigned int u) {
    return __uint_as_float(u << 16);
}

// ---------------- merged weight prep ----------------
__global__ void k_prep(const float* __restrict__ Wt, const float* __restrict__ Wd,
                       const float* __restrict__ Wa, const float* __restrict__ ba,
                       const float* __restrict__ Wb, const float* __restrict__ bb,
                       unsigned short* __restrict__ awT, unsigned short* __restrict__ wdcat,
                       unsigned short* __restrict__ wcat, float* __restrict__ biascat) {
    int e = blockIdx.x * 256 + threadIdx.x;
    if (e < CH*CH*KW) {
        int o = e / (CH*KW), c = (e / KW) % CH, k = e % KW;
        awT[(k*CH + o)*CH + c] = f2bf(Wt[e]);
        return;
    }
    int e2 = e - CH*CH*KW;
    if (e2 < NSUB*CH*CH) { wdcat[e2] = f2bf(Wd[e2]); return; }
    int e3 = e2 - NSUB*CH*CH;
    if (e3 < 6144) {
        int i = e3 / 2048, rm = (e3 >> 6) & 31, c = e3 & 63;
        wcat[e3] = f2bf((rm < 16) ? Wa[(i*ICB + rm)*CH + c] : Wb[(i*ICB + rm - 16)*CH + c]);
        return;
    }
    if (e3 < 6240) {
        int j = e3 - 6144;
        int i = j >> 5, r = j & 31;
        biascat[j] = (r < 16) ? ba[i*ICB + r] : bb[i*ICB + r - 16];
    }
}

// ---- x convert: [n][c][tv] f32 -> xbt [n][tv][c] bf16 AND xbc [n][c][tv] bf16 ----
__global__ __launch_bounds__(256) void k_xt(const float* __restrict__ x,
                                            unsigned short* __restrict__ xbt,
                                            unsigned short* __restrict__ xbc) {
    __shared__ unsigned short ls[64*66];
    int b = blockIdx.x;
    int n = b / 118, tile = b % 118;
    int tv0 = tile * 64;
    int tid = threadIdx.x;
    const float* xg = x + (long)n * CTVsz;
    for (int e = tid; e < 1024; e += 256) {
        int c = e >> 4, t4 = (e & 15) * 4;
        int tv = tv0 + t4;
        if (tv < TVsz) {
            float4 v = *(const float4*)(xg + (long)c*TVsz + tv);
            unsigned short h0 = f2bf(v.x), h1 = f2bf(v.y), h2 = f2bf(v.z), h3 = f2bf(v.w);
            ls[(t4+0)*66 + c] = h0;
            ls[(t4+1)*66 + c] = h1;
            ls[(t4+2)*66 + c] = h2;
            ls[(t4+3)*66 + c] = h3;
            *(uint2*)&xbc[((long)n*CH + c)*TVsz + tv] =
                make_uint2((unsigned)h0 | ((unsigned)h1 << 16),
                           (unsigned)h2 | ((unsigned)h3 << 16));
        }
    }
    __syncthreads();
    for (int e = tid; e < 1024; e += 256) {
        int tvl = e >> 4, c4 = (e & 15) * 4;
        int tv = tv0 + tvl;
        if (tv < TVsz) {
            unsigned int lo = *(const unsigned int*)&ls[tvl*66 + c4];
            unsigned int hi = *(const unsigned int*)&ls[tvl*66 + c4 + 2];
            *(uint2*)&xbt[((long)n*TVsz + tv)*CH + c4] = make_uint2(lo, hi);
        }
    }
}

// ---------------- attention: emb MFMA -> LDS -> Gram MFMA -> atomics --------
// emb sized for 25 v-slots (was 32): LDS 68->53.7 KB => 3 blocks/CU
__global__ __launch_bounds__(256) void k_attn(
    const unsigned short* __restrict__ xbt, const unsigned short* __restrict__ wcat,
    const float* __restrict__ biascat, float* __restrict__ Mbuf)
{
    __shared__ __align__(16) char emb[25*32*ATC*2];   // 51200 B
    __shared__ float gram[625];
    int b = blockIdx.x;
    int i   = b / (NB*ATCN);
    int rem = b % (NB*ATCN);
    int n = rem / ATCN, tc = rem % ATCN;
    int t0 = tc * ATC;
    int tid = threadIdx.x;
    int wv = tid >> 6, l = tid & 63, l15 = l & 15, lhi = l >> 4;

    for (int e = tid; e < 625; e += 256) gram[e] = 0.f;

    s16x8 wf[2][2];
    #pragma unroll
    for (int mf = 0; mf < 2; ++mf)
        #pragma unroll
        for (int kc = 0; kc < 2; ++kc)
            wf[mf][kc] = *(const s16x8*)(wcat + ((i*32 + mf*16 + l15)*64 + kc*32 + lhi*8));
    float bs[2][4];
    #pragma unroll
    for (int mf = 0; mf < 2; ++mf)
        #pragma unroll
        for (int r = 0; r < 4; ++r)
            bs[mf][r] = biascat[i*32 + mf*16 + lhi*4 + r];

    const unsigned short* xb = xbt + (long)n * TVsz * CH;
    for (int v = wv; v < 25; v += 4) {
        f32x4 ae[2][2];
        #pragma unroll
        for (int mf = 0; mf < 2; ++mf)
            #pragma unroll
            for (int nf = 0; nf < 2; ++nf)
                ae[mf][nf] = (f32x4){0.f,0.f,0.f,0.f};
        #pragma unroll
        for (int nf = 0; nf < 2; ++nf) {
            int t = t0 + nf*16 + l15;
            int tcl = t < TF ? t : TF-1;
            const unsigned short* bp = xb + ((long)tcl*VJ + v)*CH;
            s16x8 b0 = *(const s16x8*)(bp + lhi*8);
            s16x8 b1 = *(const s16x8*)(bp + 32 + lhi*8);
            #pragma unroll
            for (int mf = 0; mf < 2; ++mf) {
                ae[mf][nf] = __builtin_amdgcn_mfma_f32_16x16x32_bf16(wf[mf][0], b0, ae[mf][nf], 0,0,0);
                ae[mf][nf] = __builtin_amdgcn_mfma_f32_16x16x32_bf16(wf[mf][1], b1, ae[mf][nf], 0,0,0);
            }
        }
        #pragma unroll
        for (int mf = 0; mf < 2; ++mf)
            #pragma unroll
            for (int nf = 0; nf < 2; ++nf)
                #pragma unroll
                for (int r = 0; r < 4; ++r) {
                    int t  = t0 + nf*16 + l15;
                    int tl = nf*16 + l15;
                    int m  = mf*16 + lhi*4 + r;
                    float val = (t < TF) ? (ae[mf][nf][r] + bs[mf][r]) : 0.f;
                    int byte = (((v*32 + m)*ATC + tl)*2) ^ ((v&7)<<4);
                    *(unsigned short*)(emb + byte) = f2bf(val);
                }
    }
    __syncthreads();

    f32x4 ag[2][2];
    #pragma unroll
    for (int mu = 0; mu < 2; ++mu)
        #pragma unroll
        for (int nw = 0; nw < 2; ++nw)
            ag[mu][nw] = (f32x4){0.f,0.f,0.f,0.f};
    #pragma unroll
    for (int oo = 0; oo < 4; ++oo) {
        int o = wv*4 + oo;
        s16x8 fa[2], fb[2];
        #pragma unroll
        for (int mu = 0; mu < 2; ++mu) {
            int u = mu*16 + l15; if (u > 24) u = 24;
            fa[mu] = *(const s16x8*)(emb + ((((u*32 + o)*ATC + lhi*8)*2) ^ ((u&7)<<4)));
        }
        #pragma unroll
        for (int nw = 0; nw < 2; ++nw) {
            int w = nw*16 + l15; if (w > 24) w = 24;
            fb[nw] = *(const s16x8*)(emb + ((((w*32 + 16 + o)*ATC + lhi*8)*2) ^ ((w&7)<<4)));
        }
        #pragma unroll
        for (int mu = 0; mu < 2; ++mu)
            #pragma unroll
            for (int nw = 0; nw < 2; ++nw)
                ag[mu][nw] = __builtin_amdgcn_mfma_f32_16x16x32_bf16(fa[mu], fb[nw], ag[mu][nw], 0,0,0);
    }
    #pragma unroll
    for (int mu = 0; mu < 2; ++mu)
        #pragma unroll
        for (int nw = 0; nw < 2; ++nw)
            #pragma unroll
            for (int r = 0; r < 4; ++r) {
                int u = mu*16 + lhi*4 + r;
                int w = nw*16 + l15;
                if (u < 25 && w < 25)
                    atomicAdd(&gram[u*25 + w], ag[mu][nw][r]);
            }
    __syncthreads();
    for (int e = tid; e < 625; e += 256)
        atomicAdd(&Mbuf[(i*NB + n)*625 + e], gram[e]);
}

// ---- column softmax + A+PA -> pre-padded bf16 attnbf [n][i][v:32][u:40] ----
__global__ void k_softmax(const float* __restrict__ A, const float* __restrict__ PA,
                          const float* __restrict__ Mbuf,
                          unsigned short* __restrict__ attnbf) {
    int b = blockIdx.x;          // = i*NB + n
    int i = b / NB, n = b % NB;
    int w = threadIdx.x;         // v (0..31)
    unsigned short* row = attnbf + (((long)n*NSUB + i)*32 + w)*40;
    if (w >= 25) {
        if (w < 32) {
            #pragma unroll
            for (int u = 0; u < 40; ++u) row[u] = 0;
        }
        return;
    }
    const float* M = Mbuf + b*625;
    const float scale = 1.0f / (float)(ICB * TF);
    float col[25];
    float mx = -1e30f;
    #pragma unroll
    for (int u = 0; u < 25; ++u) { col[u] = M[u*25 + w] * scale; mx = fmaxf(mx, col[u]); }
    float s = 0.f;
    #pragma unroll
    for (int u = 0; u < 25; ++u) { col[u] = __expf(col[u] - mx); s += col[u]; }
    float inv = 1.0f / s;
    #pragma unroll
    for (int u = 0; u < 25; ++u)
        row[u] = f2bf(col[u]*inv + A[i*625 + u*25 + w] + PA[i*625 + u*25 + w]);
    #pragma unroll
    for (int u = 25; u < 40; ++u) row[u] = 0;
}

// ---- fused y (round-9 version): swapped GEMM1 + bpermute z-transpose + GEMM2,
//      scattered [n][o][tv] stores, shfl-reduced BN1 stats. ----
__global__ __launch_bounds__(256) void k_yz(
    const unsigned short* __restrict__ xbc, const unsigned short* __restrict__ attnbf,
    const unsigned short* __restrict__ wdcat, const float* __restrict__ bd,
    unsigned short* __restrict__ ybuf, float* __restrict__ s1, float* __restrict__ s2)
{
    __shared__ __align__(16) unsigned short attnT[NSUB*32*40];   // 15360 B
    __shared__ float ss[64], sq[64];

    int b = blockIdx.x;
    int n = b / 75, tq = b % 75;
    int tid = threadIdx.x;
    int wv = tid >> 6, l = tid & 63, l15 = l & 15, lhi = l >> 4;

    if (tid < 64) { ss[tid] = 0.f; sq[tid] = 0.f; }
    {
        const uint4* srcp = (const uint4*)(attnbf + (long)n * (NSUB*32*40));
        uint4* dstp = (uint4*)attnT;
        for (int e = tid; e < 480; e += 256) dstp[e] = srcp[e];
    }
    __syncthreads();

    int tg = tq*4 + wv;
    const unsigned short* xr = xbc + (long)n*CTVsz + tg*25;
    s16x8 afx[4];
    #pragma unroll
    for (int mf = 0; mf < 4; ++mf)
        afx[mf] = *(const s16x8*)(xr + (long)(mf*16 + l15)*TVsz + lhi*8);

    f32x4 acc2[4][2];
    #pragma unroll
    for (int mf = 0; mf < 4; ++mf)
        #pragma unroll
        for (int nf = 0; nf < 2; ++nf)
            acc2[mf][nf] = (f32x4){0.f,0.f,0.f,0.f};

    int srcA4 = (l15 + 32*(lhi & 1)) << 2;
    int srcB4 = srcA4 + 64;
    bool hsel = (lhi & 2) != 0;

    const f32x4 zero4 = (f32x4){0.f,0.f,0.f,0.f};
    for (int i = 0; i < NSUB; ++i) {
        s16x8 bfa0 = *(const s16x8*)(attnT + (i*32 + l15)*40 + lhi*8);
        s16x8 bfa1 = *(const s16x8*)(attnT + (i*32 + 16 + l15)*40 + lhi*8);
        f32x4 zacc[4][2];
        #pragma unroll
        for (int mf = 0; mf < 4; ++mf) {
            zacc[mf][0] = __builtin_amdgcn_mfma_f32_16x16x32_bf16(afx[mf], bfa0, zero4, 0,0,0);
            zacc[mf][1] = __builtin_amdgcn_mfma_f32_16x16x32_bf16(afx[mf], bfa1, zero4, 0,0,0);
        }
        unsigned pk[4][2][2];
        #pragma unroll
        for (int mf = 0; mf < 4; ++mf)
            #pragma unroll
            for (int nf = 0; nf < 2; ++nf) {
                pk[mf][nf][0] = (unsigned)f2bf(zacc[mf][nf][0]) | ((unsigned)f2bf(zacc[mf][nf][1]) << 16);
                pk[mf][nf][1] = (unsigned)f2bf(zacc[mf][nf][2]) | ((unsigned)f2bf(zacc[mf][nf][3]) << 16);
            }
        #pragma unroll
        for (int kc = 0; kc < 2; ++kc) {
            s16x8 bz[2];
            #pragma unroll
            for (int nf = 0; nf < 2; ++nf) {
                unsigned dw0, dw1, dw2, dw3;
                {
                    unsigned a0 = (unsigned)__builtin_amdgcn_ds_bpermute(srcA4, (int)pk[kc*2+0][nf][0]);
                    unsigned a1 = (unsigned)__builtin_amdgcn_ds_bpermute(srcA4, (int)pk[kc*2+1][nf][0]);
                    unsigned b0 = (unsigned)__builtin_amdgcn_ds_bpermute(srcB4, (int)pk[kc*2+0][nf][0]);
                    unsigned b1 = (unsigned)__builtin_amdgcn_ds_bpermute(srcB4, (int)pk[kc*2+1][nf][0]);
                    dw0 = hsel ? a1 : a0;
                    dw2 = hsel ? b1 : b0;
                }
                {
                    unsigned a0 = (unsigned)__builtin_amdgcn_ds_bpermute(srcA4, (int)pk[kc*2+0][nf][1]);
                    unsigned a1 = (unsigned)__builtin_amdgcn_ds_bpermute(srcA4, (int)pk[kc*2+1][nf][1]);
                    unsigned b0 = (unsigned)__builtin_amdgcn_ds_bpermute(srcB4, (int)pk[kc*2+0][nf][1]);
                    unsigned b1 = (unsigned)__builtin_amdgcn_ds_bpermute(srcB4, (int)pk[kc*2+1][nf][1]);
                    dw1 = hsel ? a1 : a0;
                    dw3 = hsel ? b1 : b0;
                }
                union { s16x8 v; unsigned u[4]; } tmp;
                tmp.u[0] = dw0; tmp.u[1] = dw1; tmp.u[2] = dw2; tmp.u[3] = dw3;
                bz[nf] = tmp.v;
            }
            #pragma unroll
            for (int mf2 = 0; mf2 < 4; ++mf2) {
                s16x8 afw = *(const s16x8*)(wdcat + ((i*CH + mf2*16 + l15)*CH + kc*32 + lhi*8));
                acc2[mf2][0] = __builtin_amdgcn_mfma_f32_16x16x32_bf16(afw, bz[0], acc2[mf2][0], 0,0,0);
                acc2[mf2][1] = __builtin_amdgcn_mfma_f32_16x16x32_bf16(afw, bz[1], acc2[mf2][1], 0,0,0);
            }
        }
    }

    #pragma unroll
    for (int mf = 0; mf < 4; ++mf) {
        #pragma unroll
        for (int r = 0; r < 4; ++r) {
            int o = mf*16 + lhi*4 + r;
            float bds = bd[o] + bd[CH + o] + bd[2*CH + o];
            float p = 0.f, q = 0.f;
            #pragma unroll
            for (int nf = 0; nf < 2; ++nf) {
                int v = nf*16 + l15;
                if (v < VJ) {
                    float val = acc2[mf][nf][r] + bds;
                    ybuf[((long)n*CH + o)*TVsz + tg*25 + v] = f2bf(val);
                    p += val; q += val*val;
                }
            }
            p += __shfl_xor(p, 1, 64); q += __shfl_xor(q, 1, 64);
            p += __shfl_xor(p, 2, 64); q += __shfl_xor(q, 2, 64);
            p += __shfl_xor(p, 4, 64); q += __shfl_xor(q, 4, 64);
            p += __shfl_xor(p, 8, 64); q += __shfl_xor(q, 8, 64);
            if (l15 == 0) { atomicAdd(&ss[o], p); atomicAdd(&sq[o], q); }
        }
    }
    __syncthreads();
    if (tid < 64) { atomicAdd(&s1[tid], ss[tid]); atomicAdd(&s2[tid], sq[tid]); }
}

// ------ y = relu(bn1(y)+x) -> bf16, t-major layout [n][v][t][c] -------------
__global__ __launch_bounds__(256) void k_bn1t(
    const float* __restrict__ x, const float* __restrict__ g1, const float* __restrict__ b1,
    const float* __restrict__ s1, const float* __restrict__ s2,
    const unsigned short* __restrict__ yb, unsigned short* __restrict__ ybt)
{
    __shared__ unsigned short ls[64*66];
    int b = blockIdx.x;
    int n = b / 118, tile = b % 118;
    int tv0 = tile * 64;
    const float invN = 1.0f / (float)PCCOUNT;
    int tid = threadIdx.x;

    for (int e = tid; e < 1024; e += 256) {
        int c = e >> 4, t4 = (e & 15) * 4;
        int tv = tv0 + t4;
        if (tv < TVsz) {
            long gbase = (long)n*CTVsz + (long)c*TVsz;
            float m  = s1[c] * invN;
            float vr = s2[c] * invN - m*m;
            float sc = rsqrtf(vr + EPSB) * g1[c];
            float bc = b1[c];
            uint2 yv = *(const uint2*)(yb + gbase + tv);
            float4 xv = *(const float4*)(x + gbase + tv);
            ls[(t4+0)*66 + c] = f2bf(fmaxf((bf2f(yv.x & 0xffffu) - m)*sc + bc + xv.x, 0.f));
            ls[(t4+1)*66 + c] = f2bf(fmaxf((bf2f(yv.x >> 16)     - m)*sc + bc + xv.y, 0.f));
            ls[(t4+2)*66 + c] = f2bf(fmaxf((bf2f(yv.y & 0xffffu) - m)*sc + bc + xv.z, 0.f));
            ls[(t4+3)*66 + c] = f2bf(fmaxf((bf2f(yv.y >> 16)     - m)*sc + bc + xv.w, 0.f));
        }
    }
    __syncthreads();
    for (int e = tid; e < 1024; e += 256) {
        int tvl = e >> 4, c4 = (e & 15) * 4;
        int tv = tv0 + tvl;
        if (tv < TVsz) {
            int v = tv % 25, t = tv / 25;
            unsigned int lo = *(const unsigned int*)&ls[tvl*66 + c4];
            unsigned int hi = *(const unsigned int*)&ls[tvl*66 + c4 + 2];
            *(uint2*)&ybt[(((long)n*VJ + v)*TF + t)*CH + c4] = make_uint2(lo, hi);
        }
    }
}

// ------- temporal conv: block=(n,v), full t, 8 waves x acc[4][3], BN2 stats ----
#define TCROWS 316

__global__ __launch_bounds__(512) void k_tconv(
    const unsigned short* __restrict__ ybt, const unsigned short* __restrict__ awT,
    const float* __restrict__ bt, unsigned short* __restrict__ ycb,
    float* __restrict__ s1, float* __restrict__ s2)
{
    __shared__ __align__(16) char ys[TCROWS*128];   // 40.4 KB, XOR-swizzled
    __shared__ float ss[64], sq[64];
    int b = blockIdx.x;
    int n = b / VJ, v = b % VJ;
    int tid = threadIdx.x;
    int wv = tid >> 6, l = tid & 63, l15 = l & 15, lhi = l >> 4;
    if (tid < 64) { ss[tid] = 0.f; sq[tid] = 0.f; }

    const char* src = (const char*)(ybt + (((long)n*VJ + v)*TF)*CH);
    for (int qq = tid; qq < TCROWS*8; qq += 512) {
        int row = qq >> 3;
        int cb  = (qq & 7) << 4;
        int tg = row - 4;
        uint4 val = make_uint4(0u,0u,0u,0u);
        if (tg >= 0 && tg < TF)
            val = *(const uint4*)(src + (long)tg*128 + cb);
        *(uint4*)(ys + row*128 + (cb ^ ((row & 7) << 4))) = val;
    }
    __syncthreads();

    int wt0 = wv * 38;            // wave covers t in [wt0, wt0+38) ∩ [0,300)
    const short* aw = (const short*)awT;

    f32x4 acc[4][3];
    #pragma unroll
    for (int mf = 0; mf < 4; ++mf)
        #pragma unroll
        for (int nf = 0; nf < 3; ++nf)
            acc[mf][nf] = (f32x4){0.f,0.f,0.f,0.f};

    for (int tap = 0; tap < KW; ++tap) {
        #pragma unroll
        for (int kc = 0; kc < 2; ++kc) {
            s16x8 af[4], bfr[3];
            #pragma unroll
            for (int mf = 0; mf < 4; ++mf)
                af[mf] = *(const s16x8*)(aw + ((tap*CH + mf*16 + l15)*CH + kc*32 + lhi*8));
            #pragma unroll
            for (int nf = 0; nf < 3; ++nf) {
                int rloc = wt0 + nf*16 + l15 + tap;   // can exceed staged rows on last wave
                if (rloc > TCROWS-1) rloc = TCROWS-1; // clamp: garbage masked at store
                int cb = (kc*64 + lhi*16) ^ ((rloc & 7) << 4);
                bfr[nf] = *(const s16x8*)(ys + rloc*128 + cb);
            }
            #pragma unroll
            for (int mf = 0; mf < 4; ++mf)
                #pragma unroll
                for (int nf = 0; nf < 3; ++nf)
                    acc[mf][nf] = __builtin_amdgcn_mfma_f32_16x16x32_bf16(
                        af[mf], bfr[nf], acc[mf][nf], 0, 0, 0);
        }
    }

    #pragma unroll
    for (int mf = 0; mf < 4; ++mf) {
        #pragma unroll
        for (int r = 0; r < 4; ++r) {
            int o = mf*16 + lhi*4 + r;
            float bo = bt[o];
            float p = 0.f, q = 0.f;
            #pragma unroll
            for (int nf = 0; nf < 3; ++nf) {
                int tle = nf*16 + l15;
                int tg2 = wt0 + tle;
                if (tle < 38 && tg2 < TF) {
                    float val = acc[mf][nf][r] + bo;
                    ycb[(((long)n*CH + o)*VJ + v)*TF + tg2] = f2bf(val);
                    p += val; q += val*val;
                }
            }
            p += __shfl_xor(p, 1, 64); q += __shfl_xor(q, 1, 64);
            p += __shfl_xor(p, 2, 64); q += __shfl_xor(q, 2, 64);
            p += __shfl_xor(p, 4, 64); q += __shfl_xor(q, 4, 64);
            p += __shfl_xor(p, 8, 64); q += __shfl_xor(q, 8, 64);
            if (l15 == 0) { atomicAdd(&ss[o], p); atomicAdd(&sq[o], q); }
        }
    }
    __syncthreads();
    if (tid < 64) { atomicAdd(&s1[tid], ss[tid]); atomicAdd(&s2[tid], sq[tid]); }
}

// ------- out = relu(bn2(yc)+x): block=(n,c), LDS v<->t transpose ------------
__global__ __launch_bounds__(256) void k_out(
    const float* __restrict__ x, const float* __restrict__ g2, const float* __restrict__ b2,
    const float* __restrict__ s1, const float* __restrict__ s2,
    const unsigned short* __restrict__ ycb, float* __restrict__ out)
{
    __shared__ float ls[VJ*305];
    const float invN = 1.0f / (float)PCCOUNT;
    int b = blockIdx.x;
    int n = b >> 6, c = b & 63;
    int tid = threadIdx.x;

    float m  = s1[c] * invN;
    float vr = s2[c] * invN - m*m;
    float rs = rsqrtf(vr + EPSB) * g2[c];
    float bc = b2[c];

    const uint2* yc = (const uint2*)(ycb + ((long)n*CH + c)*TVsz);
    for (int e = tid; e < TVsz/4; e += 256) {
        uint2 d = yc[e];
        int base = e*4;
        int v = base / TF, t = base % TF;
        float* lp = &ls[v*305 + t];
        lp[0] = (bf2f(d.x & 0xffffu) - m)*rs + bc;
        lp[1] = (bf2f(d.x >> 16)     - m)*rs + bc;
        lp[2] = (bf2f(d.y & 0xffffu) - m)*rs + bc;
        lp[3] = (bf2f(d.y >> 16)     - m)*rs + bc;
    }
    __syncthreads();

    long gbase = ((long)n*CH + c)*TVsz;
    for (int e = tid; e < TVsz/4; e += 256) {
        int tv = e*4;
        float4 xv = *(const float4*)(x + gbase + tv);
        float4 ov;
        { int v = (tv+0) % 25, t = (tv+0) / 25; ov.x = fmaxf(ls[v*305 + t] + xv.x, 0.f); }
        { int v = (tv+1) % 25, t = (tv+1) / 25; ov.y = fmaxf(ls[v*305 + t] + xv.y, 0.f); }
        { int v = (tv+2) % 25, t = (tv+2) / 25; ov.z = fmaxf(ls[v*305 + t] + xv.z, 0.f); }
        { int v = (tv+3) % 25, t = (tv+3) / 25; ov.w = fmaxf(ls[v*305 + t] + xv.w, 0.f); }
        *(float4*)(out + gbase + tv) = ov;
    }
}

extern "C" void kernel_launch(void* const* d_in, const int* in_sizes, int n_in,
                              void* d_out, int out_size, void* d_ws, size_t ws_size,
                              hipStream_t stream) {
    const float* x  = (const float*)d_in[0];
    const float* A  = (const float*)d_in[1];
    const float* PA = (const float*)d_in[2];
    const float* Wa = (const float*)d_in[3];
    const float* ba = (const float*)d_in[4];
    const float* Wb = (const float*)d_in[5];
    const float* bb = (const float*)d_in[6];
    const float* Wd = (const float*)d_in[7];
    const float* bd = (const float*)d_in[8];
    const float* g1 = (const float*)d_in[9];
    const float* b1 = (const float*)d_in[10];
    const float* Wt = (const float*)d_in[11];
    const float* bt = (const float*)d_in[12];
    const float* g2 = (const float*)d_in[13];
    const float* b2 = (const float*)d_in[14];

    float* ws    = (float*)d_ws;
    float* Mbuf  = ws;                                         // [0, 60000)
    float* stats = ws + 60000;                                 // [60000, 60256)
    unsigned short* attnbf = (unsigned short*)(ws + 60256);    // -> 121696
    unsigned short* wdcat  = (unsigned short*)(ws + 121696);   // -> 127840
    unsigned short* wcat   = (unsigned short*)(ws + 127840);   // -> 130912
    float* biascat = ws + 130912;                              // -> 131008
    unsigned short* awT    = (unsigned short*)(ws + 131008);   // -> 149440
    unsigned short* xbt    = (unsigned short*)(ws + 149440);   // 15.36M sh -> 7829440
    unsigned short* xbc    = (unsigned short*)(ws + 7829440);  // 15.36M sh -> 15509440
    unsigned short* ybuf   = (unsigned short*)(ws + 15509440); // [n][o][tv] -> 23189440
    // overlays:
    unsigned short* ybt = xbc;    // after k_yz (xbc dead once y computed)
    unsigned short* ycb = ybuf;   // after k_bn1t (ybuf dead once transposed)

    hipMemsetAsync(Mbuf, 0, (60000 + 256)*sizeof(float), stream);
    k_prep<<<217, 256, 0, stream>>>(Wt, Wd, Wa, ba, Wb, bb, awT, wdcat, wcat, biascat);
    k_xt<<<NB*118, 256, 0, stream>>>(x, xbt, xbc);
    k_attn<<<NSUB*NB*ATCN, 256, 0, stream>>>(xbt, wcat, biascat, Mbuf);
    k_softmax<<<NSUB*NB, 32, 0, stream>>>(A, PA, Mbuf, attnbf);
    k_yz<<<NB*75, 256, 0, stream>>>(xbc, attnbf, wdcat, bd, ybuf, stats, stats + 64);
    k_bn1t<<<NB*118, 256, 0, stream>>>(x, g1, b1, stats, stats + 64, ybuf, ybt);
    k_tconv<<<NB*VJ, 512, 0, stream>>>(ybt, awT, bt, ycb, stats + 128, stats + 192);
    k_out<<<NB*CH, 256, 0, stream>>>(x, g2, b2, stats + 128, stats + 192, ycb, (float*)d_out);
}

// Round 12
// 263.050 us; speedup vs baseline: 1.1665x; 1.1665x over previous
//
#include <hip/hip_runtime.h>
#include <hip/hip_bf16.h>

#define NB 32
#define CH 64
#define TF 300
#define VJ 25
#define NSUB 3
#define ICB 16
#define KW 9
#define EPSB 1e-5f

#define TVsz (TF*VJ)          // 7500
#define CTVsz (CH*TF*VJ)      // 480000
#define TOTAL (NB*CTVsz)      // 15360000
#define PCCOUNT (NB*TF*VJ)    // 240000

#define ATC 32                // t per attention chunk
#define ATCN 10               // ceil(300/32)

typedef __attribute__((ext_vector_type(8))) short s16x8;
typedef __attribute__((ext_vector_type(4))) float f32x4;

__device__ __forceinline__ unsigned short f2bf(float v) {
    __hip_bfloat16 h = __float2bfloat16(v);
    return *(unsigned short*)&h;
}
__device__ __forceinline__ float bf2f(unsigned int u) {
    return __uint_as_float(u << 16);
}

// ---------------- merged weight prep ----------------
__global__ void k_prep(const float* __restrict__ Wt, const float* __restrict__ Wd,
                       const float* __restrict__ Wa, const float* __restrict__ ba,
                       const float* __restrict__ Wb, const float* __restrict__ bb,
                       unsigned short* __restrict__ awT, unsigned short* __restrict__ wdcat,
                       unsigned short* __restrict__ wcat, float* __restrict__ biascat) {
    int e = blockIdx.x * 256 + threadIdx.x;
    if (e < CH*CH*KW) {
        int o = e / (CH*KW), c = (e / KW) % CH, k = e % KW;
        awT[(k*CH + o)*CH + c] = f2bf(Wt[e]);
        return;
    }
    int e2 = e - CH*CH*KW;
    if (e2 < NSUB*CH*CH) { wdcat[e2] = f2bf(Wd[e2]); return; }
    int e3 = e2 - NSUB*CH*CH;
    if (e3 < 6144) {
        int i = e3 / 2048, rm = (e3 >> 6) & 31, c = e3 & 63;
        wcat[e3] = f2bf((rm < 16) ? Wa[(i*ICB + rm)*CH + c] : Wb[(i*ICB + rm - 16)*CH + c]);
        return;
    }
    if (e3 < 6240) {
        int j = e3 - 6144;
        int i = j >> 5, r = j & 31;
        biascat[j] = (r < 16) ? ba[i*ICB + r] : bb[i*ICB + r - 16];
    }
}

// ---- x convert: [n][c][tv] f32 -> xbt [n][tv][c] bf16 AND xbc [n][c][tv] bf16 ----
__global__ __launch_bounds__(256) void k_xt(const float* __restrict__ x,
                                            unsigned short* __restrict__ xbt,
                                            unsigned short* __restrict__ xbc) {
    __shared__ unsigned short ls[64*66];
    int b = blockIdx.x;
    int n = b / 118, tile = b % 118;
    int tv0 = tile * 64;
    int tid = threadIdx.x;
    const float* xg = x + (long)n * CTVsz;
    for (int e = tid; e < 1024; e += 256) {
        int c = e >> 4, t4 = (e & 15) * 4;
        int tv = tv0 + t4;
        if (tv < TVsz) {
            float4 v = *(const float4*)(xg + (long)c*TVsz + tv);
            unsigned short h0 = f2bf(v.x), h1 = f2bf(v.y), h2 = f2bf(v.z), h3 = f2bf(v.w);
            ls[(t4+0)*66 + c] = h0;
            ls[(t4+1)*66 + c] = h1;
            ls[(t4+2)*66 + c] = h2;
            ls[(t4+3)*66 + c] = h3;
            *(uint2*)&xbc[((long)n*CH + c)*TVsz + tv] =
                make_uint2((unsigned)h0 | ((unsigned)h1 << 16),
                           (unsigned)h2 | ((unsigned)h3 << 16));
        }
    }
    __syncthreads();
    for (int e = tid; e < 1024; e += 256) {
        int tvl = e >> 4, c4 = (e & 15) * 4;
        int tv = tv0 + tvl;
        if (tv < TVsz) {
            unsigned int lo = *(const unsigned int*)&ls[tvl*66 + c4];
            unsigned int hi = *(const unsigned int*)&ls[tvl*66 + c4 + 2];
            *(uint2*)&xbt[((long)n*TVsz + tv)*CH + c4] = make_uint2(lo, hi);
        }
    }
}

// ---------------- attention: emb MFMA -> LDS -> Gram MFMA -> atomics --------
__global__ __launch_bounds__(256) void k_attn(
    const unsigned short* __restrict__ xbt, const unsigned short* __restrict__ wcat,
    const float* __restrict__ biascat, float* __restrict__ Mbuf)
{
    __shared__ __align__(16) char emb[32*32*ATC*2];
    __shared__ float gram[625];
    int b = blockIdx.x;
    int i   = b / (NB*ATCN);
    int rem = b % (NB*ATCN);
    int n = rem / ATCN, tc = rem % ATCN;
    int t0 = tc * ATC;
    int tid = threadIdx.x;
    int wv = tid >> 6, l = tid & 63, l15 = l & 15, lhi = l >> 4;

    for (int e = tid; e < 625; e += 256) gram[e] = 0.f;

    s16x8 wf[2][2];
    #pragma unroll
    for (int mf = 0; mf < 2; ++mf)
        #pragma unroll
        for (int kc = 0; kc < 2; ++kc)
            wf[mf][kc] = *(const s16x8*)(wcat + ((i*32 + mf*16 + l15)*64 + kc*32 + lhi*8));
    float bs[2][4];
    #pragma unroll
    for (int mf = 0; mf < 2; ++mf)
        #pragma unroll
        for (int r = 0; r < 4; ++r)
            bs[mf][r] = biascat[i*32 + mf*16 + lhi*4 + r];

    const unsigned short* xb = xbt + (long)n * TVsz * CH;
    for (int v = wv; v < 25; v += 4) {
        f32x4 ae[2][2];
        #pragma unroll
        for (int mf = 0; mf < 2; ++mf)
            #pragma unroll
            for (int nf = 0; nf < 2; ++nf)
                ae[mf][nf] = (f32x4){0.f,0.f,0.f,0.f};
        #pragma unroll
        for (int nf = 0; nf < 2; ++nf) {
            int t = t0 + nf*16 + l15;
            int tcl = t < TF ? t : TF-1;
            const unsigned short* bp = xb + ((long)tcl*VJ + v)*CH;
            s16x8 b0 = *(const s16x8*)(bp + lhi*8);
            s16x8 b1 = *(const s16x8*)(bp + 32 + lhi*8);
            #pragma unroll
            for (int mf = 0; mf < 2; ++mf) {
                ae[mf][nf] = __builtin_amdgcn_mfma_f32_16x16x32_bf16(wf[mf][0], b0, ae[mf][nf], 0,0,0);
                ae[mf][nf] = __builtin_amdgcn_mfma_f32_16x16x32_bf16(wf[mf][1], b1, ae[mf][nf], 0,0,0);
            }
        }
        #pragma unroll
        for (int mf = 0; mf < 2; ++mf)
            #pragma unroll
            for (int nf = 0; nf < 2; ++nf)
                #pragma unroll
                for (int r = 0; r < 4; ++r) {
                    int t  = t0 + nf*16 + l15;
                    int tl = nf*16 + l15;
                    int m  = mf*16 + lhi*4 + r;
                    float val = (t < TF) ? (ae[mf][nf][r] + bs[mf][r]) : 0.f;
                    int byte = (((v*32 + m)*ATC + tl)*2) ^ ((v&7)<<4);
                    *(unsigned short*)(emb + byte) = f2bf(val);
                }
    }
    __syncthreads();

    f32x4 ag[2][2];
    #pragma unroll
    for (int mu = 0; mu < 2; ++mu)
        #pragma unroll
        for (int nw = 0; nw < 2; ++nw)
            ag[mu][nw] = (f32x4){0.f,0.f,0.f,0.f};
    #pragma unroll
    for (int oo = 0; oo < 4; ++oo) {
        int o = wv*4 + oo;
        s16x8 fa[2], fb[2];
        #pragma unroll
        for (int mu = 0; mu < 2; ++mu) {
            int u = mu*16 + l15; if (u > 24) u = 24;
            fa[mu] = *(const s16x8*)(emb + ((((u*32 + o)*ATC + lhi*8)*2) ^ ((u&7)<<4)));
        }
        #pragma unroll
        for (int nw = 0; nw < 2; ++nw) {
            int w = nw*16 + l15; if (w > 24) w = 24;
            fb[nw] = *(const s16x8*)(emb + ((((w*32 + 16 + o)*ATC + lhi*8)*2) ^ ((w&7)<<4)));
        }
        #pragma unroll
        for (int mu = 0; mu < 2; ++mu)
            #pragma unroll
            for (int nw = 0; nw < 2; ++nw)
                ag[mu][nw] = __builtin_amdgcn_mfma_f32_16x16x32_bf16(fa[mu], fb[nw], ag[mu][nw], 0,0,0);
    }
    #pragma unroll
    for (int mu = 0; mu < 2; ++mu)
        #pragma unroll
        for (int nw = 0; nw < 2; ++nw)
            #pragma unroll
            for (int r = 0; r < 4; ++r) {
                int u = mu*16 + lhi*4 + r;
                int w = nw*16 + l15;
                if (u < 25 && w < 25)
                    atomicAdd(&gram[u*25 + w], ag[mu][nw][r]);
            }
    __syncthreads();
    for (int e = tid; e < 625; e += 256)
        atomicAdd(&Mbuf[(i*NB + n)*625 + e], gram[e]);
}

// ---- column softmax + A+PA -> pre-padded bf16 attnbf [n][i][v:32][u:40] ----
__global__ void k_softmax(const float* __restrict__ A, const float* __restrict__ PA,
                          const float* __restrict__ Mbuf,
                          unsigned short* __restrict__ attnbf) {
    int b = blockIdx.x;          // = i*NB + n
    int i = b / NB, n = b % NB;
    int w = threadIdx.x;         // v (0..31)
    unsigned short* row = attnbf + (((long)n*NSUB + i)*32 + w)*40;
    if (w >= 25) {
        if (w < 32) {
            #pragma unroll
            for (int u = 0; u < 40; ++u) row[u] = 0;
        }
        return;
    }
    const float* M = Mbuf + b*625;
    const float scale = 1.0f / (float)(ICB * TF);
    float col[25];
    float mx = -1e30f;
    #pragma unroll
    for (int u = 0; u < 25; ++u) { col[u] = M[u*25 + w] * scale; mx = fmaxf(mx, col[u]); }
    float s = 0.f;
    #pragma unroll
    for (int u = 0; u < 25; ++u) { col[u] = __expf(col[u] - mx); s += col[u]; }
    float inv = 1.0f / s;
    #pragma unroll
    for (int u = 0; u < 25; ++u)
        row[u] = f2bf(col[u]*inv + A[i*625 + u*25 + w] + PA[i*625 + u*25 + w]);
    #pragma unroll
    for (int u = 25; u < 40; ++u) row[u] = 0;
}

// ---- fused y (round-9): swapped GEMM1 + bpermute z-transpose + GEMM2,
//      scattered [n][o][tv] stores, shfl-reduced BN1 stats. ----
__global__ __launch_bounds__(256) void k_yz(
    const unsigned short* __restrict__ xbc, const unsigned short* __restrict__ attnbf,
    const unsigned short* __restrict__ wdcat, const float* __restrict__ bd,
    unsigned short* __restrict__ ybuf, float* __restrict__ s1, float* __restrict__ s2)
{
    __shared__ __align__(16) unsigned short attnT[NSUB*32*40];   // 15360 B
    __shared__ float ss[64], sq[64];

    int b = blockIdx.x;
    int n = b / 75, tq = b % 75;
    int tid = threadIdx.x;
    int wv = tid >> 6, l = tid & 63, l15 = l & 15, lhi = l >> 4;

    if (tid < 64) { ss[tid] = 0.f; sq[tid] = 0.f; }
    {
        const uint4* srcp = (const uint4*)(attnbf + (long)n * (NSUB*32*40));
        uint4* dstp = (uint4*)attnT;
        for (int e = tid; e < 480; e += 256) dstp[e] = srcp[e];
    }
    __syncthreads();

    int tg = tq*4 + wv;
    const unsigned short* xr = xbc + (long)n*CTVsz + tg*25;
    s16x8 afx[4];
    #pragma unroll
    for (int mf = 0; mf < 4; ++mf)
        afx[mf] = *(const s16x8*)(xr + (long)(mf*16 + l15)*TVsz + lhi*8);

    f32x4 acc2[4][2];
    #pragma unroll
    for (int mf = 0; mf < 4; ++mf)
        #pragma unroll
        for (int nf = 0; nf < 2; ++nf)
            acc2[mf][nf] = (f32x4){0.f,0.f,0.f,0.f};

    int srcA4 = (l15 + 32*(lhi & 1)) << 2;
    int srcB4 = srcA4 + 64;
    bool hsel = (lhi & 2) != 0;

    const f32x4 zero4 = (f32x4){0.f,0.f,0.f,0.f};
    for (int i = 0; i < NSUB; ++i) {
        s16x8 bfa0 = *(const s16x8*)(attnT + (i*32 + l15)*40 + lhi*8);
        s16x8 bfa1 = *(const s16x8*)(attnT + (i*32 + 16 + l15)*40 + lhi*8);
        f32x4 zacc[4][2];
        #pragma unroll
        for (int mf = 0; mf < 4; ++mf) {
            zacc[mf][0] = __builtin_amdgcn_mfma_f32_16x16x32_bf16(afx[mf], bfa0, zero4, 0,0,0);
            zacc[mf][1] = __builtin_amdgcn_mfma_f32_16x16x32_bf16(afx[mf], bfa1, zero4, 0,0,0);
        }
        unsigned pk[4][2][2];
        #pragma unroll
        for (int mf = 0; mf < 4; ++mf)
            #pragma unroll
            for (int nf = 0; nf < 2; ++nf) {
                pk[mf][nf][0] = (unsigned)f2bf(zacc[mf][nf][0]) | ((unsigned)f2bf(zacc[mf][nf][1]) << 16);
                pk[mf][nf][1] = (unsigned)f2bf(zacc[mf][nf][2]) | ((unsigned)f2bf(zacc[mf][nf][3]) << 16);
            }
        #pragma unroll
        for (int kc = 0; kc < 2; ++kc) {
            s16x8 bz[2];
            #pragma unroll
            for (int nf = 0; nf < 2; ++nf) {
                unsigned dw0, dw1, dw2, dw3;
                {
                    unsigned a0 = (unsigned)__builtin_amdgcn_ds_bpermute(srcA4, (int)pk[kc*2+0][nf][0]);
                    unsigned a1 = (unsigned)__builtin_amdgcn_ds_bpermute(srcA4, (int)pk[kc*2+1][nf][0]);
                    unsigned b0 = (unsigned)__builtin_amdgcn_ds_bpermute(srcB4, (int)pk[kc*2+0][nf][0]);
                    unsigned b1 = (unsigned)__builtin_amdgcn_ds_bpermute(srcB4, (int)pk[kc*2+1][nf][0]);
                    dw0 = hsel ? a1 : a0;
                    dw2 = hsel ? b1 : b0;
                }
                {
                    unsigned a0 = (unsigned)__builtin_amdgcn_ds_bpermute(srcA4, (int)pk[kc*2+0][nf][1]);
                    unsigned a1 = (unsigned)__builtin_amdgcn_ds_bpermute(srcA4, (int)pk[kc*2+1][nf][1]);
                    unsigned b0 = (unsigned)__builtin_amdgcn_ds_bpermute(srcB4, (int)pk[kc*2+0][nf][1]);
                    unsigned b1 = (unsigned)__builtin_amdgcn_ds_bpermute(srcB4, (int)pk[kc*2+1][nf][1]);
                    dw1 = hsel ? a1 : a0;
                    dw3 = hsel ? b1 : b0;
                }
                union { s16x8 v; unsigned u[4]; } tmp;
                tmp.u[0] = dw0; tmp.u[1] = dw1; tmp.u[2] = dw2; tmp.u[3] = dw3;
                bz[nf] = tmp.v;
            }
            #pragma unroll
            for (int mf2 = 0; mf2 < 4; ++mf2) {
                s16x8 afw = *(const s16x8*)(wdcat + ((i*CH + mf2*16 + l15)*CH + kc*32 + lhi*8));
                acc2[mf2][0] = __builtin_amdgcn_mfma_f32_16x16x32_bf16(afw, bz[0], acc2[mf2][0], 0,0,0);
                acc2[mf2][1] = __builtin_amdgcn_mfma_f32_16x16x32_bf16(afw, bz[1], acc2[mf2][1], 0,0,0);
            }
        }
    }

    #pragma unroll
    for (int mf = 0; mf < 4; ++mf) {
        #pragma unroll
        for (int r = 0; r < 4; ++r) {
            int o = mf*16 + lhi*4 + r;
            float bds = bd[o] + bd[CH + o] + bd[2*CH + o];
            float p = 0.f, q = 0.f;
            #pragma unroll
            for (int nf = 0; nf < 2; ++nf) {
                int v = nf*16 + l15;
                if (v < VJ) {
                    float val = acc2[mf][nf][r] + bds;
                    ybuf[((long)n*CH + o)*TVsz + tg*25 + v] = f2bf(val);
                    p += val; q += val*val;
                }
            }
            p += __shfl_xor(p, 1, 64); q += __shfl_xor(q, 1, 64);
            p += __shfl_xor(p, 2, 64); q += __shfl_xor(q, 2, 64);
            p += __shfl_xor(p, 4, 64); q += __shfl_xor(q, 4, 64);
            p += __shfl_xor(p, 8, 64); q += __shfl_xor(q, 8, 64);
            if (l15 == 0) { atomicAdd(&ss[o], p); atomicAdd(&sq[o], q); }
        }
    }
    __syncthreads();
    if (tid < 64) { atomicAdd(&s1[tid], ss[tid]); atomicAdd(&s2[tid], sq[tid]); }
}

// ------ y = relu(bn1(y)+x) -> bf16, t-major [n][v][t][c]; residual from xbc bf16 ----
__global__ __launch_bounds__(256) void k_bn1t(
    const unsigned short* __restrict__ xc, const float* __restrict__ g1, const float* __restrict__ b1,
    const float* __restrict__ s1, const float* __restrict__ s2,
    const unsigned short* __restrict__ yb, unsigned short* __restrict__ ybt)
{
    __shared__ unsigned short ls[64*66];
    int b = blockIdx.x;
    int n = b / 118, tile = b % 118;
    int tv0 = tile * 64;
    const float invN = 1.0f / (float)PCCOUNT;
    int tid = threadIdx.x;

    for (int e = tid; e < 1024; e += 256) {
        int c = e >> 4, t4 = (e & 15) * 4;
        int tv = tv0 + t4;
        if (tv < TVsz) {
            long gbase = (long)n*CTVsz + (long)c*TVsz;
            float m  = s1[c] * invN;
            float vr = s2[c] * invN - m*m;
            float sc = rsqrtf(vr + EPSB) * g1[c];
            float bc = b1[c];
            uint2 yv = *(const uint2*)(yb + gbase + tv);
            uint2 xv = *(const uint2*)(xc + gbase + tv);
            ls[(t4+0)*66 + c] = f2bf(fmaxf((bf2f(yv.x & 0xffffu) - m)*sc + bc + bf2f(xv.x & 0xffffu), 0.f));
            ls[(t4+1)*66 + c] = f2bf(fmaxf((bf2f(yv.x >> 16)     - m)*sc + bc + bf2f(xv.x >> 16),     0.f));
            ls[(t4+2)*66 + c] = f2bf(fmaxf((bf2f(yv.y & 0xffffu) - m)*sc + bc + bf2f(xv.y & 0xffffu), 0.f));
            ls[(t4+3)*66 + c] = f2bf(fmaxf((bf2f(yv.y >> 16)     - m)*sc + bc + bf2f(xv.y >> 16),     0.f));
        }
    }
    __syncthreads();
    for (int e = tid; e < 1024; e += 256) {
        int tvl = e >> 4, c4 = (e & 15) * 4;
        int tv = tv0 + tvl;
        if (tv < TVsz) {
            int v = tv % 25, t = tv / 25;
            unsigned int lo = *(const unsigned int*)&ls[tvl*66 + c4];
            unsigned int hi = *(const unsigned int*)&ls[tvl*66 + c4 + 2];
            *(uint2*)&ybt[(((long)n*VJ + v)*TF + t)*CH + c4] = make_uint2(lo, hi);
        }
    }
}

// ------- temporal conv (round-9): block=(n,v), full t, 4 waves x acc[4][5] ----
#define TCROWS 316

__global__ __launch_bounds__(256) void k_tconv(
    const unsigned short* __restrict__ ybt, const unsigned short* __restrict__ awT,
    const float* __restrict__ bt, unsigned short* __restrict__ ycb,
    float* __restrict__ s1, float* __restrict__ s2)
{
    __shared__ __align__(16) char ys[TCROWS*128];   // 40.4 KB, XOR-swizzled
    __shared__ float ss[64], sq[64];
    int b = blockIdx.x;
    int n = b / VJ, v = b % VJ;
    int tid = threadIdx.x;
    int wv = tid >> 6, l = tid & 63, l15 = l & 15, lhi = l >> 4;
    if (tid < 64) { ss[tid] = 0.f; sq[tid] = 0.f; }

    const char* src = (const char*)(ybt + (((long)n*VJ + v)*TF)*CH);
    for (int qq = tid; qq < TCROWS*8; qq += 256) {
        int row = qq >> 3;
        int cb  = (qq & 7) << 4;
        int tg = row - 4;
        uint4 val = make_uint4(0u,0u,0u,0u);
        if (tg >= 0 && tg < TF)
            val = *(const uint4*)(src + (long)tg*128 + cb);
        *(uint4*)(ys + row*128 + (cb ^ ((row & 7) << 4))) = val;
    }
    __syncthreads();

    int wt0 = wv * 75;
    const short* aw = (const short*)awT;

    f32x4 acc[4][5];
    #pragma unroll
    for (int mf = 0; mf < 4; ++mf)
        #pragma unroll
        for (int nf = 0; nf < 5; ++nf)
            acc[mf][nf] = (f32x4){0.f,0.f,0.f,0.f};

    for (int tap = 0; tap < KW; ++tap) {
        #pragma unroll
        for (int kc = 0; kc < 2; ++kc) {
            s16x8 af[4], bfr[5];
            #pragma unroll
            for (int mf = 0; mf < 4; ++mf)
                af[mf] = *(const s16x8*)(aw + ((tap*CH + mf*16 + l15)*CH + kc*32 + lhi*8));
            #pragma unroll
            for (int nf = 0; nf < 5; ++nf) {
                int rloc = wt0 + nf*16 + l15 + tap;
                int cb = (kc*64 + lhi*16) ^ ((rloc & 7) << 4);
                bfr[nf] = *(const s16x8*)(ys + rloc*128 + cb);
            }
            #pragma unroll
            for (int mf = 0; mf < 4; ++mf)
                #pragma unroll
                for (int nf = 0; nf < 5; ++nf)
                    acc[mf][nf] = __builtin_amdgcn_mfma_f32_16x16x32_bf16(
                        af[mf], bfr[nf], acc[mf][nf], 0, 0, 0);
        }
    }

    #pragma unroll
    for (int mf = 0; mf < 4; ++mf) {
        #pragma unroll
        for (int r = 0; r < 4; ++r) {
            int o = mf*16 + lhi*4 + r;
            float bo = bt[o];
            float p = 0.f, q = 0.f;
            #pragma unroll
            for (int nf = 0; nf < 5; ++nf) {
                int tle = nf*16 + l15;
                if (tle < 75) {
                    float val = acc[mf][nf][r] + bo;
                    ycb[(((long)n*CH + o)*VJ + v)*TF + wt0 + tle] = f2bf(val);
                    p += val; q += val*val;
                }
            }
            p += __shfl_xor(p, 1, 64); q += __shfl_xor(q, 1, 64);
            p += __shfl_xor(p, 2, 64); q += __shfl_xor(q, 2, 64);
            p += __shfl_xor(p, 4, 64); q += __shfl_xor(q, 4, 64);
            p += __shfl_xor(p, 8, 64); q += __shfl_xor(q, 8, 64);
            if (l15 == 0) { atomicAdd(&ss[o], p); atomicAdd(&sq[o], q); }
        }
    }
    __syncthreads();
    if (tid < 64) { atomicAdd(&s1[tid], ss[tid]); atomicAdd(&s2[tid], sq[tid]); }
}

// ------- out = relu(bn2(yc)+x): block=(n,c), LDS v<->t transpose; x from xbc bf16 ----
__global__ __launch_bounds__(256) void k_out(
    const unsigned short* __restrict__ xc, const float* __restrict__ g2, const float* __restrict__ b2,
    const float* __restrict__ s1, const float* __restrict__ s2,
    const unsigned short* __restrict__ ycb, float* __restrict__ out)
{
    __shared__ float ls[VJ*305];
    const float invN = 1.0f / (float)PCCOUNT;
    int b = blockIdx.x;
    int n = b >> 6, c = b & 63;
    int tid = threadIdx.x;

    float m  = s1[c] * invN;
    float vr = s2[c] * invN - m*m;
    float rs = rsqrtf(vr + EPSB) * g2[c];
    float bc = b2[c];

    const uint2* yc = (const uint2*)(ycb + ((long)n*CH + c)*TVsz);
    for (int e = tid; e < TVsz/4; e += 256) {
        uint2 d = yc[e];
        int base = e*4;
        int v = base / TF, t = base % TF;
        float* lp = &ls[v*305 + t];
        lp[0] = (bf2f(d.x & 0xffffu) - m)*rs + bc;
        lp[1] = (bf2f(d.x >> 16)     - m)*rs + bc;
        lp[2] = (bf2f(d.y & 0xffffu) - m)*rs + bc;
        lp[3] = (bf2f(d.y >> 16)     - m)*rs + bc;
    }
    __syncthreads();

    long gbase = ((long)n*CH + c)*TVsz;
    const uint2* xp = (const uint2*)(xc + gbase);
    for (int e = tid; e < TVsz/4; e += 256) {
        int tv = e*4;
        uint2 xv = xp[e];
        float4 ov;
        { int v = (tv+0) % 25, t = (tv+0) / 25; ov.x = fmaxf(ls[v*305 + t] + bf2f(xv.x & 0xffffu), 0.f); }
        { int v = (tv+1) % 25, t = (tv+1) / 25; ov.y = fmaxf(ls[v*305 + t] + bf2f(xv.x >> 16),     0.f); }
        { int v = (tv+2) % 25, t = (tv+2) / 25; ov.z = fmaxf(ls[v*305 + t] + bf2f(xv.y & 0xffffu), 0.f); }
        { int v = (tv+3) % 25, t = (tv+3) / 25; ov.w = fmaxf(ls[v*305 + t] + bf2f(xv.y >> 16),     0.f); }
        *(float4*)(out + gbase + tv) = ov;
    }
}

extern "C" void kernel_launch(void* const* d_in, const int* in_sizes, int n_in,
                              void* d_out, int out_size, void* d_ws, size_t ws_size,
                              hipStream_t stream) {
    const float* x  = (const float*)d_in[0];
    const float* A  = (const float*)d_in[1];
    const float* PA = (const float*)d_in[2];
    const float* Wa = (const float*)d_in[3];
    const float* ba = (const float*)d_in[4];
    const float* Wb = (const float*)d_in[5];
    const float* bb = (const float*)d_in[6];
    const float* Wd = (const float*)d_in[7];
    const float* bd = (const float*)d_in[8];
    const float* g1 = (const float*)d_in[9];
    const float* b1 = (const float*)d_in[10];
    const float* Wt = (const float*)d_in[11];
    const float* bt = (const float*)d_in[12];
    const float* g2 = (const float*)d_in[13];
    const float* b2 = (const float*)d_in[14];

    float* ws    = (float*)d_ws;
    float* Mbuf  = ws;                                         // [0, 60000)
    float* stats = ws + 60000;                                 // [60000, 60256)
    unsigned short* attnbf = (unsigned short*)(ws + 60256);    // -> 121696
    unsigned short* wdcat  = (unsigned short*)(ws + 121696);   // -> 127840
    unsigned short* wcat   = (unsigned short*)(ws + 127840);   // -> 130912
    float* biascat = ws + 130912;                              // -> 131008
    unsigned short* awT    = (unsigned short*)(ws + 131008);   // -> 149440
    unsigned short* xbt    = (unsigned short*)(ws + 149440);   // 15.36M sh -> 7829440
    unsigned short* xbc    = (unsigned short*)(ws + 7829440);  // 15.36M sh -> 15509440
    unsigned short* ybuf   = (unsigned short*)(ws + 15509440); // [n][o][tv] -> 23189440
    // overlays: xbc stays LIVE through the tail (bf16 residual for bn1t/out).
    unsigned short* ybt = xbt;    // xbt dead after k_attn
    unsigned short* ycb = ybuf;   // ybuf dead after k_bn1t

    hipMemsetAsync(Mbuf, 0, (60000 + 256)*sizeof(float), stream);
    k_prep<<<217, 256, 0, stream>>>(Wt, Wd, Wa, ba, Wb, bb, awT, wdcat, wcat, biascat);
    k_xt<<<NB*118, 256, 0, stream>>>(x, xbt, xbc);
    k_attn<<<NSUB*NB*ATCN, 256, 0, stream>>>(xbt, wcat, biascat, Mbuf);
    k_softmax<<<NSUB*NB, 32, 0, stream>>>(A, PA, Mbuf, attnbf);
    k_yz<<<NB*75, 256, 0, stream>>>(xbc, attnbf, wdcat, bd, ybuf, stats, stats + 64);
    k_bn1t<<<NB*118, 256, 0, stream>>>(xbc, g1, b1, stats, stats + 64, ybuf, ybt);
    k_tconv<<<NB*VJ, 256, 0, stream>>>(ybt, awT, bt, ycb, stats + 128, stats + 192);
    k_out<<<NB*CH, 256, 0, stream>>>(xbc, g2, b2, stats + 128, stats + 192, ycb, (float*)d_out);
}

// Round 13
// 237.843 us; speedup vs baseline: 1.2901x; 1.1060x over previous
//
#include <hip/hip_runtime.h>
#include <hip/hip_bf16.h>

#define NB 32
#define CH 64
#define TF 300
#define VJ 25
#define NSUB 3
#define ICB 16
#define KW 9
#define EPSB 1e-5f

#define TVsz (TF*VJ)          // 7500
#define CTVsz (CH*TF*VJ)      // 480000
#define TOTAL (NB*CTVsz)      // 15360000
#define PCCOUNT (NB*TF*VJ)    // 240000

#define ATC 32                // t per attention chunk
#define ATCN 10               // ceil(300/32)
#define YZBLK (NB*75)         // 2400 k_yz blocks

typedef __attribute__((ext_vector_type(8))) short s16x8;
typedef __attribute__((ext_vector_type(4))) float f32x4;

__device__ __forceinline__ unsigned short f2bf(float v) {
    __hip_bfloat16 h = __float2bfloat16(v);
    return *(unsigned short*)&h;
}
__device__ __forceinline__ float bf2f(unsigned int u) {
    return __uint_as_float(u << 16);
}

// ---------------- merged weight prep ----------------
__global__ void k_prep(const float* __restrict__ Wt, const float* __restrict__ Wd,
                       const float* __restrict__ Wa, const float* __restrict__ ba,
                       const float* __restrict__ Wb, const float* __restrict__ bb,
                       unsigned short* __restrict__ awT, unsigned short* __restrict__ wdcat,
                       unsigned short* __restrict__ wcat, float* __restrict__ biascat) {
    int e = blockIdx.x * 256 + threadIdx.x;
    if (e < CH*CH*KW) {
        int o = e / (CH*KW), c = (e / KW) % CH, k = e % KW;
        awT[(k*CH + o)*CH + c] = f2bf(Wt[e]);
        return;
    }
    int e2 = e - CH*CH*KW;
    if (e2 < NSUB*CH*CH) { wdcat[e2] = f2bf(Wd[e2]); return; }
    int e3 = e2 - NSUB*CH*CH;
    if (e3 < 6144) {
        int i = e3 / 2048, rm = (e3 >> 6) & 31, c = e3 & 63;
        wcat[e3] = f2bf((rm < 16) ? Wa[(i*ICB + rm)*CH + c] : Wb[(i*ICB + rm - 16)*CH + c]);
        return;
    }
    if (e3 < 6240) {
        int j = e3 - 6144;
        int i = j >> 5, r = j & 31;
        biascat[j] = (r < 16) ? ba[i*ICB + r] : bb[i*ICB + r - 16];
    }
}

// ---- x convert: [n][c][tv] f32 -> xbt [n][tv][c] bf16 AND xbc [n][c][tv] bf16 ----
__global__ __launch_bounds__(256) void k_xt(const float* __restrict__ x,
                                            unsigned short* __restrict__ xbt,
                                            unsigned short* __restrict__ xbc) {
    __shared__ unsigned short ls[64*66];
    int b = blockIdx.x;
    int n = b / 118, tile = b % 118;
    int tv0 = tile * 64;
    int tid = threadIdx.x;
    const float* xg = x + (long)n * CTVsz;
    for (int e = tid; e < 1024; e += 256) {
        int c = e >> 4, t4 = (e & 15) * 4;
        int tv = tv0 + t4;
        if (tv < TVsz) {
            float4 v = *(const float4*)(xg + (long)c*TVsz + tv);
            unsigned short h0 = f2bf(v.x), h1 = f2bf(v.y), h2 = f2bf(v.z), h3 = f2bf(v.w);
            ls[(t4+0)*66 + c] = h0;
            ls[(t4+1)*66 + c] = h1;
            ls[(t4+2)*66 + c] = h2;
            ls[(t4+3)*66 + c] = h3;
            *(uint2*)&xbc[((long)n*CH + c)*TVsz + tv] =
                make_uint2((unsigned)h0 | ((unsigned)h1 << 16),
                           (unsigned)h2 | ((unsigned)h3 << 16));
        }
    }
    __syncthreads();
    for (int e = tid; e < 1024; e += 256) {
        int tvl = e >> 4, c4 = (e & 15) * 4;
        int tv = tv0 + tvl;
        if (tv < TVsz) {
            unsigned int lo = *(const unsigned int*)&ls[tvl*66 + c4];
            unsigned int hi = *(const unsigned int*)&ls[tvl*66 + c4 + 2];
            *(uint2*)&xbt[((long)n*TVsz + tv)*CH + c4] = make_uint2(lo, hi);
        }
    }
}

// ---------------- attention: emb MFMA -> LDS -> Gram MFMA -> atomics --------
__global__ __launch_bounds__(256) void k_attn(
    const unsigned short* __restrict__ xbt, const unsigned short* __restrict__ wcat,
    const float* __restrict__ biascat, float* __restrict__ Mbuf)
{
    __shared__ __align__(16) char emb[32*32*ATC*2];
    __shared__ float gram[625];
    int b = blockIdx.x;
    int i   = b / (NB*ATCN);
    int rem = b % (NB*ATCN);
    int n = rem / ATCN, tc = rem % ATCN;
    int t0 = tc * ATC;
    int tid = threadIdx.x;
    int wv = tid >> 6, l = tid & 63, l15 = l & 15, lhi = l >> 4;

    for (int e = tid; e < 625; e += 256) gram[e] = 0.f;

    s16x8 wf[2][2];
    #pragma unroll
    for (int mf = 0; mf < 2; ++mf)
        #pragma unroll
        for (int kc = 0; kc < 2; ++kc)
            wf[mf][kc] = *(const s16x8*)(wcat + ((i*32 + mf*16 + l15)*64 + kc*32 + lhi*8));
    float bs[2][4];
    #pragma unroll
    for (int mf = 0; mf < 2; ++mf)
        #pragma unroll
        for (int r = 0; r < 4; ++r)
            bs[mf][r] = biascat[i*32 + mf*16 + lhi*4 + r];

    const unsigned short* xb = xbt + (long)n * TVsz * CH;
    for (int v = wv; v < 25; v += 4) {
        f32x4 ae[2][2];
        #pragma unroll
        for (int mf = 0; mf < 2; ++mf)
            #pragma unroll
            for (int nf = 0; nf < 2; ++nf)
                ae[mf][nf] = (f32x4){0.f,0.f,0.f,0.f};
        #pragma unroll
        for (int nf = 0; nf < 2; ++nf) {
            int t = t0 + nf*16 + l15;
            int tcl = t < TF ? t : TF-1;
            const unsigned short* bp = xb + ((long)tcl*VJ + v)*CH;
            s16x8 b0 = *(const s16x8*)(bp + lhi*8);
            s16x8 b1 = *(const s16x8*)(bp + 32 + lhi*8);
            #pragma unroll
            for (int mf = 0; mf < 2; ++mf) {
                ae[mf][nf] = __builtin_amdgcn_mfma_f32_16x16x32_bf16(wf[mf][0], b0, ae[mf][nf], 0,0,0);
                ae[mf][nf] = __builtin_amdgcn_mfma_f32_16x16x32_bf16(wf[mf][1], b1, ae[mf][nf], 0,0,0);
            }
        }
        #pragma unroll
        for (int mf = 0; mf < 2; ++mf)
            #pragma unroll
            for (int nf = 0; nf < 2; ++nf)
                #pragma unroll
                for (int r = 0; r < 4; ++r) {
                    int t  = t0 + nf*16 + l15;
                    int tl = nf*16 + l15;
                    int m  = mf*16 + lhi*4 + r;
                    float val = (t < TF) ? (ae[mf][nf][r] + bs[mf][r]) : 0.f;
                    int byte = (((v*32 + m)*ATC + tl)*2) ^ ((v&7)<<4);
                    *(unsigned short*)(emb + byte) = f2bf(val);
                }
    }
    __syncthreads();

    f32x4 ag[2][2];
    #pragma unroll
    for (int mu = 0; mu < 2; ++mu)
        #pragma unroll
        for (int nw = 0; nw < 2; ++nw)
            ag[mu][nw] = (f32x4){0.f,0.f,0.f,0.f};
    #pragma unroll
    for (int oo = 0; oo < 4; ++oo) {
        int o = wv*4 + oo;
        s16x8 fa[2], fb[2];
        #pragma unroll
        for (int mu = 0; mu < 2; ++mu) {
            int u = mu*16 + l15; if (u > 24) u = 24;
            fa[mu] = *(const s16x8*)(emb + ((((u*32 + o)*ATC + lhi*8)*2) ^ ((u&7)<<4)));
        }
        #pragma unroll
        for (int nw = 0; nw < 2; ++nw) {
            int w = nw*16 + l15; if (w > 24) w = 24;
            fb[nw] = *(const s16x8*)(emb + ((((w*32 + 16 + o)*ATC + lhi*8)*2) ^ ((w&7)<<4)));
        }
        #pragma unroll
        for (int mu = 0; mu < 2; ++mu)
            #pragma unroll
            for (int nw = 0; nw < 2; ++nw)
                ag[mu][nw] = __builtin_amdgcn_mfma_f32_16x16x32_bf16(fa[mu], fb[nw], ag[mu][nw], 0,0,0);
    }
    #pragma unroll
    for (int mu = 0; mu < 2; ++mu)
        #pragma unroll
        for (int nw = 0; nw < 2; ++nw)
            #pragma unroll
            for (int r = 0; r < 4; ++r) {
                int u = mu*16 + lhi*4 + r;
                int w = nw*16 + l15;
                if (u < 25 && w < 25)
                    atomicAdd(&gram[u*25 + w], ag[mu][nw][r]);
            }
    __syncthreads();
    for (int e = tid; e < 625; e += 256)
        atomicAdd(&Mbuf[(i*NB + n)*625 + e], gram[e]);
}

// ---- column softmax + A+PA -> pre-padded bf16 attnbf [n][i][v:32][u:40] ----
__global__ void k_softmax(const float* __restrict__ A, const float* __restrict__ PA,
                          const float* __restrict__ Mbuf,
                          unsigned short* __restrict__ attnbf) {
    int b = blockIdx.x;          // = i*NB + n
    int i = b / NB, n = b % NB;
    int w = threadIdx.x;         // v (0..31)
    unsigned short* row = attnbf + (((long)n*NSUB + i)*32 + w)*40;
    if (w >= 25) {
        if (w < 32) {
            #pragma unroll
            for (int u = 0; u < 40; ++u) row[u] = 0;
        }
        return;
    }
    const float* M = Mbuf + b*625;
    const float scale = 1.0f / (float)(ICB * TF);
    float col[25];
    float mx = -1e30f;
    #pragma unroll
    for (int u = 0; u < 25; ++u) { col[u] = M[u*25 + w] * scale; mx = fmaxf(mx, col[u]); }
    float s = 0.f;
    #pragma unroll
    for (int u = 0; u < 25; ++u) { col[u] = __expf(col[u] - mx); s += col[u]; }
    float inv = 1.0f / s;
    #pragma unroll
    for (int u = 0; u < 25; ++u)
        row[u] = f2bf(col[u]*inv + A[i*625 + u*25 + w] + PA[i*625 + u*25 + w]);
    #pragma unroll
    for (int u = 25; u < 40; ++u) row[u] = 0;
}

// ---- fused y: swapped GEMM1 + bpermute z-transpose + GEMM2.
//      BN1 stats -> per-block PLAIN stores (no global atomics). ----
__global__ __launch_bounds__(256) void k_yz(
    const unsigned short* __restrict__ xbc, const unsigned short* __restrict__ attnbf,
    const unsigned short* __restrict__ wdcat, const float* __restrict__ bd,
    unsigned short* __restrict__ ybuf, float* __restrict__ pstats)
{
    __shared__ __align__(16) unsigned short attnT[NSUB*32*40];   // 15360 B
    __shared__ float ss[64], sq[64];

    int b = blockIdx.x;
    int n = b / 75, tq = b % 75;
    int tid = threadIdx.x;
    int wv = tid >> 6, l = tid & 63, l15 = l & 15, lhi = l >> 4;

    if (tid < 64) { ss[tid] = 0.f; sq[tid] = 0.f; }
    {
        const uint4* srcp = (const uint4*)(attnbf + (long)n * (NSUB*32*40));
        uint4* dstp = (uint4*)attnT;
        for (int e = tid; e < 480; e += 256) dstp[e] = srcp[e];
    }
    __syncthreads();

    int tg = tq*4 + wv;
    const unsigned short* xr = xbc + (long)n*CTVsz + tg*25;
    s16x8 afx[4];
    #pragma unroll
    for (int mf = 0; mf < 4; ++mf)
        afx[mf] = *(const s16x8*)(xr + (long)(mf*16 + l15)*TVsz + lhi*8);

    f32x4 acc2[4][2];
    #pragma unroll
    for (int mf = 0; mf < 4; ++mf)
        #pragma unroll
        for (int nf = 0; nf < 2; ++nf)
            acc2[mf][nf] = (f32x4){0.f,0.f,0.f,0.f};

    int srcA4 = (l15 + 32*(lhi & 1)) << 2;
    int srcB4 = srcA4 + 64;
    bool hsel = (lhi & 2) != 0;

    const f32x4 zero4 = (f32x4){0.f,0.f,0.f,0.f};
    for (int i = 0; i < NSUB; ++i) {
        s16x8 bfa0 = *(const s16x8*)(attnT + (i*32 + l15)*40 + lhi*8);
        s16x8 bfa1 = *(const s16x8*)(attnT + (i*32 + 16 + l15)*40 + lhi*8);
        f32x4 zacc[4][2];
        #pragma unroll
        for (int mf = 0; mf < 4; ++mf) {
            zacc[mf][0] = __builtin_amdgcn_mfma_f32_16x16x32_bf16(afx[mf], bfa0, zero4, 0,0,0);
            zacc[mf][1] = __builtin_amdgcn_mfma_f32_16x16x32_bf16(afx[mf], bfa1, zero4, 0,0,0);
        }
        unsigned pk[4][2][2];
        #pragma unroll
        for (int mf = 0; mf < 4; ++mf)
            #pragma unroll
            for (int nf = 0; nf < 2; ++nf) {
                pk[mf][nf][0] = (unsigned)f2bf(zacc[mf][nf][0]) | ((unsigned)f2bf(zacc[mf][nf][1]) << 16);
                pk[mf][nf][1] = (unsigned)f2bf(zacc[mf][nf][2]) | ((unsigned)f2bf(zacc[mf][nf][3]) << 16);
            }
        #pragma unroll
        for (int kc = 0; kc < 2; ++kc) {
            s16x8 bz[2];
            #pragma unroll
            for (int nf = 0; nf < 2; ++nf) {
                unsigned dw0, dw1, dw2, dw3;
                {
                    unsigned a0 = (unsigned)__builtin_amdgcn_ds_bpermute(srcA4, (int)pk[kc*2+0][nf][0]);
                    unsigned a1 = (unsigned)__builtin_amdgcn_ds_bpermute(srcA4, (int)pk[kc*2+1][nf][0]);
                    unsigned b0 = (unsigned)__builtin_amdgcn_ds_bpermute(srcB4, (int)pk[kc*2+0][nf][0]);
                    unsigned b1 = (unsigned)__builtin_amdgcn_ds_bpermute(srcB4, (int)pk[kc*2+1][nf][0]);
                    dw0 = hsel ? a1 : a0;
                    dw2 = hsel ? b1 : b0;
                }
                {
                    unsigned a0 = (unsigned)__builtin_amdgcn_ds_bpermute(srcA4, (int)pk[kc*2+0][nf][1]);
                    unsigned a1 = (unsigned)__builtin_amdgcn_ds_bpermute(srcA4, (int)pk[kc*2+1][nf][1]);
                    unsigned b0 = (unsigned)__builtin_amdgcn_ds_bpermute(srcB4, (int)pk[kc*2+0][nf][1]);
                    unsigned b1 = (unsigned)__builtin_amdgcn_ds_bpermute(srcB4, (int)pk[kc*2+1][nf][1]);
                    dw1 = hsel ? a1 : a0;
                    dw3 = hsel ? b1 : b0;
                }
                union { s16x8 v; unsigned u[4]; } tmp;
                tmp.u[0] = dw0; tmp.u[1] = dw1; tmp.u[2] = dw2; tmp.u[3] = dw3;
                bz[nf] = tmp.v;
            }
            #pragma unroll
            for (int mf2 = 0; mf2 < 4; ++mf2) {
                s16x8 afw = *(const s16x8*)(wdcat + ((i*CH + mf2*16 + l15)*CH + kc*32 + lhi*8));
                acc2[mf2][0] = __builtin_amdgcn_mfma_f32_16x16x32_bf16(afw, bz[0], acc2[mf2][0], 0,0,0);
                acc2[mf2][1] = __builtin_amdgcn_mfma_f32_16x16x32_bf16(afw, bz[1], acc2[mf2][1], 0,0,0);
            }
        }
    }

    #pragma unroll
    for (int mf = 0; mf < 4; ++mf) {
        #pragma unroll
        for (int r = 0; r < 4; ++r) {
            int o = mf*16 + lhi*4 + r;
            float bds = bd[o] + bd[CH + o] + bd[2*CH + o];
            float p = 0.f, q = 0.f;
            #pragma unroll
            for (int nf = 0; nf < 2; ++nf) {
                int v = nf*16 + l15;
                if (v < VJ) {
                    float val = acc2[mf][nf][r] + bds;
                    ybuf[((long)n*CH + o)*TVsz + tg*25 + v] = f2bf(val);
                    p += val; q += val*val;
                }
            }
            p += __shfl_xor(p, 1, 64); q += __shfl_xor(q, 1, 64);
            p += __shfl_xor(p, 2, 64); q += __shfl_xor(q, 2, 64);
            p += __shfl_xor(p, 4, 64); q += __shfl_xor(q, 4, 64);
            p += __shfl_xor(p, 8, 64); q += __shfl_xor(q, 8, 64);
            if (l15 == 0) { atomicAdd(&ss[o], p); atomicAdd(&sq[o], q); }
        }
    }
    __syncthreads();
    if (tid < 64) {
        pstats[(long)b*128 + tid]      = ss[tid];
        pstats[(long)b*128 + 64 + tid] = sq[tid];
    }
}

// ---- reduce per-block partial stats -> stats (plain stores) ----
__global__ __launch_bounds__(256) void k_red(const float* __restrict__ pstats,
                                             float* __restrict__ s1, float* __restrict__ s2) {
    int col = blockIdx.x;   // 0..127: 0-63 sum, 64-127 sumsq
    int tid = threadIdx.x;
    float s = 0.f;
    for (int e = tid; e < YZBLK; e += 256)
        s += pstats[(long)e*128 + col];
    #pragma unroll
    for (int off = 32; off; off >>= 1) s += __shfl_down(s, off, 64);
    __shared__ float rs[4];
    int wid = tid >> 6, lane = tid & 63;
    if (lane == 0) rs[wid] = s;
    __syncthreads();
    if (tid == 0) {
        float t = rs[0]+rs[1]+rs[2]+rs[3];
        if (col < 64) s1[col] = t; else s2[col-64] = t;
    }
}

// ------ y = relu(bn1(y)+x) -> bf16, t-major [n][v][t][c]; residual from xbc bf16 ----
__global__ __launch_bounds__(256) void k_bn1t(
    const unsigned short* __restrict__ xc, const float* __restrict__ g1, const float* __restrict__ b1,
    const float* __restrict__ s1, const float* __restrict__ s2,
    const unsigned short* __restrict__ yb, unsigned short* __restrict__ ybt)
{
    __shared__ unsigned short ls[64*66];
    int b = blockIdx.x;
    int n = b / 118, tile = b % 118;
    int tv0 = tile * 64;
    const float invN = 1.0f / (float)PCCOUNT;
    int tid = threadIdx.x;

    for (int e = tid; e < 1024; e += 256) {
        int c = e >> 4, t4 = (e & 15) * 4;
        int tv = tv0 + t4;
        if (tv < TVsz) {
            long gbase = (long)n*CTVsz + (long)c*TVsz;
            float m  = s1[c] * invN;
            float vr = s2[c] * invN - m*m;
            float sc = rsqrtf(vr + EPSB) * g1[c];
            float bc = b1[c];
            uint2 yv = *(const uint2*)(yb + gbase + tv);
            uint2 xv = *(const uint2*)(xc + gbase + tv);
            ls[(t4+0)*66 + c] = f2bf(fmaxf((bf2f(yv.x & 0xffffu) - m)*sc + bc + bf2f(xv.x & 0xffffu), 0.f));
            ls[(t4+1)*66 + c] = f2bf(fmaxf((bf2f(yv.x >> 16)     - m)*sc + bc + bf2f(xv.x >> 16),     0.f));
            ls[(t4+2)*66 + c] = f2bf(fmaxf((bf2f(yv.y & 0xffffu) - m)*sc + bc + bf2f(xv.y & 0xffffu), 0.f));
            ls[(t4+3)*66 + c] = f2bf(fmaxf((bf2f(yv.y >> 16)     - m)*sc + bc + bf2f(xv.y >> 16),     0.f));
        }
    }
    __syncthreads();
    for (int e = tid; e < 1024; e += 256) {
        int tvl = e >> 4, c4 = (e & 15) * 4;
        int tv = tv0 + tvl;
        if (tv < TVsz) {
            int v = tv % 25, t = tv / 25;
            unsigned int lo = *(const unsigned int*)&ls[tvl*66 + c4];
            unsigned int hi = *(const unsigned int*)&ls[tvl*66 + c4 + 2];
            *(uint2*)&ybt[(((long)n*VJ + v)*TF + t)*CH + c4] = make_uint2(lo, hi);
        }
    }
}

// ------- temporal conv: block=(n,v), full t, 4 waves x acc[4][5], BN2 stats ----
#define TCROWS 316

__global__ __launch_bounds__(256) void k_tconv(
    const unsigned short* __restrict__ ybt, const unsigned short* __restrict__ awT,
    const float* __restrict__ bt, unsigned short* __restrict__ ycb,
    float* __restrict__ s1, float* __restrict__ s2)
{
    __shared__ __align__(16) char ys[TCROWS*128];   // 40.4 KB, XOR-swizzled
    __shared__ float ss[64], sq[64];
    int b = blockIdx.x;
    int n = b / VJ, v = b % VJ;
    int tid = threadIdx.x;
    int wv = tid >> 6, l = tid & 63, l15 = l & 15, lhi = l >> 4;
    if (tid < 64) { ss[tid] = 0.f; sq[tid] = 0.f; }

    const char* src = (const char*)(ybt + (((long)n*VJ + v)*TF)*CH);
    for (int qq = tid; qq < TCROWS*8; qq += 256) {
        int row = qq >> 3;
        int cb  = (qq & 7) << 4;
        int tg = row - 4;
        uint4 val = make_uint4(0u,0u,0u,0u);
        if (tg >= 0 && tg < TF)
            val = *(const uint4*)(src + (long)tg*128 + cb);
        *(uint4*)(ys + row*128 + (cb ^ ((row & 7) << 4))) = val;
    }
    __syncthreads();

    int wt0 = wv * 75;
    const short* aw = (const short*)awT;

    f32x4 acc[4][5];
    #pragma unroll
    for (int mf = 0; mf < 4; ++mf)
        #pragma unroll
        for (int nf = 0; nf < 5; ++nf)
            acc[mf][nf] = (f32x4){0.f,0.f,0.f,0.f};

    for (int tap = 0; tap < KW; ++tap) {
        #pragma unroll
        for (int kc = 0; kc < 2; ++kc) {
            s16x8 af[4], bfr[5];
            #pragma unroll
            for (int mf = 0; mf < 4; ++mf)
                af[mf] = *(const s16x8*)(aw + ((tap*CH + mf*16 + l15)*CH + kc*32 + lhi*8));
            #pragma unroll
            for (int nf = 0; nf < 5; ++nf) {
                int rloc = wt0 + nf*16 + l15 + tap;
                int cb = (kc*64 + lhi*16) ^ ((rloc & 7) << 4);
                bfr[nf] = *(const s16x8*)(ys + rloc*128 + cb);
            }
            #pragma unroll
            for (int mf = 0; mf < 4; ++mf)
                #pragma unroll
                for (int nf = 0; nf < 5; ++nf)
                    acc[mf][nf] = __builtin_amdgcn_mfma_f32_16x16x32_bf16(
                        af[mf], bfr[nf], acc[mf][nf], 0, 0, 0);
        }
    }

    #pragma unroll
    for (int mf = 0; mf < 4; ++mf) {
        #pragma unroll
        for (int r = 0; r < 4; ++r) {
            int o = mf*16 + lhi*4 + r;
            float bo = bt[o];
            float p = 0.f, q = 0.f;
            #pragma unroll
            for (int nf = 0; nf < 5; ++nf) {
                int tle = nf*16 + l15;
                if (tle < 75) {
                    float val = acc[mf][nf][r] + bo;
                    ycb[(((long)n*CH + o)*VJ + v)*TF + wt0 + tle] = f2bf(val);
                    p += val; q += val*val;
                }
            }
            p += __shfl_xor(p, 1, 64); q += __shfl_xor(q, 1, 64);
            p += __shfl_xor(p, 2, 64); q += __shfl_xor(q, 2, 64);
            p += __shfl_xor(p, 4, 64); q += __shfl_xor(q, 4, 64);
            p += __shfl_xor(p, 8, 64); q += __shfl_xor(q, 8, 64);
            if (l15 == 0) { atomicAdd(&ss[o], p); atomicAdd(&sq[o], q); }
        }
    }
    __syncthreads();
    if (tid < 64) { atomicAdd(&s1[tid], ss[tid]); atomicAdd(&s2[tid], sq[tid]); }
}

// ------- out = relu(bn2(yc)+x): block=(n,c), LDS v<->t transpose; x from xbc bf16 ----
__global__ __launch_bounds__(256) void k_out(
    const unsigned short* __restrict__ xc, const float* __restrict__ g2, const float* __restrict__ b2,
    const float* __restrict__ s1, const float* __restrict__ s2,
    const unsigned short* __restrict__ ycb, float* __restrict__ out)
{
    __shared__ float ls[VJ*305];
    const float invN = 1.0f / (float)PCCOUNT;
    int b = blockIdx.x;
    int n = b >> 6, c = b & 63;
    int tid = threadIdx.x;

    float m  = s1[c] * invN;
    float vr = s2[c] * invN - m*m;
    float rs = rsqrtf(vr + EPSB) * g2[c];
    float bc = b2[c];

    const uint2* yc = (const uint2*)(ycb + ((long)n*CH + c)*TVsz);
    for (int e = tid; e < TVsz/4; e += 256) {
        uint2 d = yc[e];
        int base = e*4;
        int v = base / TF, t = base % TF;
        float* lp = &ls[v*305 + t];
        lp[0] = (bf2f(d.x & 0xffffu) - m)*rs + bc;
        lp[1] = (bf2f(d.x >> 16)     - m)*rs + bc;
        lp[2] = (bf2f(d.y & 0xffffu) - m)*rs + bc;
        lp[3] = (bf2f(d.y >> 16)     - m)*rs + bc;
    }
    __syncthreads();

    long gbase = ((long)n*CH + c)*TVsz;
    const uint2* xp = (const uint2*)(xc + gbase);
    for (int e = tid; e < TVsz/4; e += 256) {
        int tv = e*4;
        uint2 xv = xp[e];
        float4 ov;
        { int v = (tv+0) % 25, t = (tv+0) / 25; ov.x = fmaxf(ls[v*305 + t] + bf2f(xv.x & 0xffffu), 0.f); }
        { int v = (tv+1) % 25, t = (tv+1) / 25; ov.y = fmaxf(ls[v*305 + t] + bf2f(xv.x >> 16),     0.f); }
        { int v = (tv+2) % 25, t = (tv+2) / 25; ov.z = fmaxf(ls[v*305 + t] + bf2f(xv.y & 0xffffu), 0.f); }
        { int v = (tv+3) % 25, t = (tv+3) / 25; ov.w = fmaxf(ls[v*305 + t] + bf2f(xv.y >> 16),     0.f); }
        *(float4*)(out + gbase + tv) = ov;
    }
}

extern "C" void kernel_launch(void* const* d_in, const int* in_sizes, int n_in,
                              void* d_out, int out_size, void* d_ws, size_t ws_size,
                              hipStream_t stream) {
    const float* x  = (const float*)d_in[0];
    const float* A  = (const float*)d_in[1];
    const float* PA = (const float*)d_in[2];
    const float* Wa = (const float*)d_in[3];
    const float* ba = (const float*)d_in[4];
    const float* Wb = (const float*)d_in[5];
    const float* bb = (const float*)d_in[6];
    const float* Wd = (const float*)d_in[7];
    const float* bd = (const float*)d_in[8];
    const float* g1 = (const float*)d_in[9];
    const float* b1 = (const float*)d_in[10];
    const float* Wt = (const float*)d_in[11];
    const float* bt = (const float*)d_in[12];
    const float* g2 = (const float*)d_in[13];
    const float* b2 = (const float*)d_in[14];

    float* ws    = (float*)d_ws;
    float* Mbuf  = ws;                                         // [0, 60000)
    float* stats = ws + 60000;                                 // [60000, 60256)
    unsigned short* attnbf = (unsigned short*)(ws + 60256);    // -> 121696
    unsigned short* wdcat  = (unsigned short*)(ws + 121696);   // -> 127840
    unsigned short* wcat   = (unsigned short*)(ws + 127840);   // -> 130912
    float* biascat = ws + 130912;                              // -> 131008
    unsigned short* awT    = (unsigned short*)(ws + 131008);   // -> 149440
    unsigned short* xbt    = (unsigned short*)(ws + 149440);   // 15.36M sh -> 7829440
    unsigned short* xbc    = (unsigned short*)(ws + 7829440);  // 15.36M sh -> 15509440
    unsigned short* ybuf   = (unsigned short*)(ws + 15509440); // [n][o][tv] -> 23189440
    float* pstats = ws + 23189440;                             // 2400*128 -> 23496640
    // overlays: xbc stays LIVE through the tail (bf16 residual for bn1t/out).
    unsigned short* ybt = xbt;    // xbt dead after k_attn
    unsigned short* ycb = ybuf;   // ybuf dead after k_bn1t

    hipMemsetAsync(Mbuf, 0, (60000 + 256)*sizeof(float), stream);
    k_prep<<<217, 256, 0, stream>>>(Wt, Wd, Wa, ba, Wb, bb, awT, wdcat, wcat, biascat);
    k_xt<<<NB*118, 256, 0, stream>>>(x, xbt, xbc);
    k_attn<<<NSUB*NB*ATCN, 256, 0, stream>>>(xbt, wcat, biascat, Mbuf);
    k_softmax<<<NSUB*NB, 32, 0, stream>>>(A, PA, Mbuf, attnbf);
    k_yz<<<YZBLK, 256, 0, stream>>>(xbc, attnbf, wdcat, bd, ybuf, pstats);
    k_red<<<128, 256, 0, stream>>>(pstats, stats, stats + 64);
    k_bn1t<<<NB*118, 256, 0, stream>>>(xbc, g1, b1, stats, stats + 64, ybuf, ybt);
    k_tconv<<<NB*VJ, 256, 0, stream>>>(ybt, awT, bt, ycb, stats + 128, stats + 192);
    k_out<<<NB*CH, 256, 0, stream>>>(xbc, g2, b2, stats + 128, stats + 192, ycb, (float*)d_out);
}

// Round 14
// 229.987 us; speedup vs baseline: 1.3342x; 1.0342x over previous
//
#include <hip/hip_runtime.h>
#include <hip/hip_bf16.h>

#define NB 32
#define CH 64
#define TF 300
#define VJ 25
#define NSUB 3
#define ICB 16
#define KW 9
#define EPSB 1e-5f

#define TVsz (TF*VJ)          // 7500
#define CTVsz (CH*TF*VJ)      // 480000
#define TOTAL (NB*CTVsz)      // 15360000
#define PCCOUNT (NB*TF*VJ)    // 240000

#define ATC 32                // t per attention chunk
#define ATCN 10               // ceil(300/32)
#define YZBLK (NB*75)         // 2400 k_yz blocks
#define TCBLK (NB*VJ)         // 800 k_tconv blocks

typedef __attribute__((ext_vector_type(8))) short s16x8;
typedef __attribute__((ext_vector_type(4))) float f32x4;

__device__ __forceinline__ unsigned short f2bf(float v) {
    __hip_bfloat16 h = __float2bfloat16(v);
    return *(unsigned short*)&h;
}
__device__ __forceinline__ float bf2f(unsigned int u) {
    return __uint_as_float(u << 16);
}

// ---------------- merged weight prep ----------------
__global__ void k_prep(const float* __restrict__ Wt, const float* __restrict__ Wd,
                       const float* __restrict__ Wa, const float* __restrict__ ba,
                       const float* __restrict__ Wb, const float* __restrict__ bb,
                       unsigned short* __restrict__ awT, unsigned short* __restrict__ wdcat,
                       unsigned short* __restrict__ wcat, float* __restrict__ biascat) {
    int e = blockIdx.x * 256 + threadIdx.x;
    if (e < CH*CH*KW) {
        int o = e / (CH*KW), c = (e / KW) % CH, k = e % KW;
        awT[(k*CH + o)*CH + c] = f2bf(Wt[e]);
        return;
    }
    int e2 = e - CH*CH*KW;
    if (e2 < NSUB*CH*CH) { wdcat[e2] = f2bf(Wd[e2]); return; }
    int e3 = e2 - NSUB*CH*CH;
    if (e3 < 6144) {
        int i = e3 / 2048, rm = (e3 >> 6) & 31, c = e3 & 63;
        wcat[e3] = f2bf((rm < 16) ? Wa[(i*ICB + rm)*CH + c] : Wb[(i*ICB + rm - 16)*CH + c]);
        return;
    }
    if (e3 < 6240) {
        int j = e3 - 6144;
        int i = j >> 5, r = j & 31;
        biascat[j] = (r < 16) ? ba[i*ICB + r] : bb[i*ICB + r - 16];
    }
}

// ---- x convert: [n][c][tv] f32 -> xbt [n][tv][c] bf16 AND xbc [n][c][tv] bf16 ----
__global__ __launch_bounds__(256) void k_xt(const float* __restrict__ x,
                                            unsigned short* __restrict__ xbt,
                                            unsigned short* __restrict__ xbc) {
    __shared__ unsigned short ls[64*66];
    int b = blockIdx.x;
    int n = b / 118, tile = b % 118;
    int tv0 = tile * 64;
    int tid = threadIdx.x;
    const float* xg = x + (long)n * CTVsz;
    for (int e = tid; e < 1024; e += 256) {
        int c = e >> 4, t4 = (e & 15) * 4;
        int tv = tv0 + t4;
        if (tv < TVsz) {
            float4 v = *(const float4*)(xg + (long)c*TVsz + tv);
            unsigned short h0 = f2bf(v.x), h1 = f2bf(v.y), h2 = f2bf(v.z), h3 = f2bf(v.w);
            ls[(t4+0)*66 + c] = h0;
            ls[(t4+1)*66 + c] = h1;
            ls[(t4+2)*66 + c] = h2;
            ls[(t4+3)*66 + c] = h3;
            *(uint2*)&xbc[((long)n*CH + c)*TVsz + tv] =
                make_uint2((unsigned)h0 | ((unsigned)h1 << 16),
                           (unsigned)h2 | ((unsigned)h3 << 16));
        }
    }
    __syncthreads();
    for (int e = tid; e < 1024; e += 256) {
        int tvl = e >> 4, c4 = (e & 15) * 4;
        int tv = tv0 + tvl;
        if (tv < TVsz) {
            unsigned int lo = *(const unsigned int*)&ls[tvl*66 + c4];
            unsigned int hi = *(const unsigned int*)&ls[tvl*66 + c4 + 2];
            *(uint2*)&xbt[((long)n*TVsz + tv)*CH + c4] = make_uint2(lo, hi);
        }
    }
}

// ---------------- attention: emb MFMA -> LDS -> Gram MFMA -> PLAIN partial store ----
__global__ __launch_bounds__(256) void k_attn(
    const unsigned short* __restrict__ xbt, const unsigned short* __restrict__ wcat,
    const float* __restrict__ biascat, float* __restrict__ Mpart)
{
    __shared__ __align__(16) char emb[32*32*ATC*2];
    __shared__ float gram[625];
    int b = blockIdx.x;
    int i   = b / (NB*ATCN);
    int rem = b % (NB*ATCN);
    int n = rem / ATCN, tc = rem % ATCN;
    int t0 = tc * ATC;
    int tid = threadIdx.x;
    int wv = tid >> 6, l = tid & 63, l15 = l & 15, lhi = l >> 4;

    for (int e = tid; e < 625; e += 256) gram[e] = 0.f;

    s16x8 wf[2][2];
    #pragma unroll
    for (int mf = 0; mf < 2; ++mf)
        #pragma unroll
        for (int kc = 0; kc < 2; ++kc)
            wf[mf][kc] = *(const s16x8*)(wcat + ((i*32 + mf*16 + l15)*64 + kc*32 + lhi*8));
    float bs[2][4];
    #pragma unroll
    for (int mf = 0; mf < 2; ++mf)
        #pragma unroll
        for (int r = 0; r < 4; ++r)
            bs[mf][r] = biascat[i*32 + mf*16 + lhi*4 + r];

    const unsigned short* xb = xbt + (long)n * TVsz * CH;
    for (int v = wv; v < 25; v += 4) {
        f32x4 ae[2][2];
        #pragma unroll
        for (int mf = 0; mf < 2; ++mf)
            #pragma unroll
            for (int nf = 0; nf < 2; ++nf)
                ae[mf][nf] = (f32x4){0.f,0.f,0.f,0.f};
        #pragma unroll
        for (int nf = 0; nf < 2; ++nf) {
            int t = t0 + nf*16 + l15;
            int tcl = t < TF ? t : TF-1;
            const unsigned short* bp = xb + ((long)tcl*VJ + v)*CH;
            s16x8 b0 = *(const s16x8*)(bp + lhi*8);
            s16x8 b1 = *(const s16x8*)(bp + 32 + lhi*8);
            #pragma unroll
            for (int mf = 0; mf < 2; ++mf) {
                ae[mf][nf] = __builtin_amdgcn_mfma_f32_16x16x32_bf16(wf[mf][0], b0, ae[mf][nf], 0,0,0);
                ae[mf][nf] = __builtin_amdgcn_mfma_f32_16x16x32_bf16(wf[mf][1], b1, ae[mf][nf], 0,0,0);
            }
        }
        #pragma unroll
        for (int mf = 0; mf < 2; ++mf)
            #pragma unroll
            for (int nf = 0; nf < 2; ++nf)
                #pragma unroll
                for (int r = 0; r < 4; ++r) {
                    int t  = t0 + nf*16 + l15;
                    int tl = nf*16 + l15;
                    int m  = mf*16 + lhi*4 + r;
                    float val = (t < TF) ? (ae[mf][nf][r] + bs[mf][r]) : 0.f;
                    int byte = (((v*32 + m)*ATC + tl)*2) ^ ((v&7)<<4);
                    *(unsigned short*)(emb + byte) = f2bf(val);
                }
    }
    __syncthreads();

    f32x4 ag[2][2];
    #pragma unroll
    for (int mu = 0; mu < 2; ++mu)
        #pragma unroll
        for (int nw = 0; nw < 2; ++nw)
            ag[mu][nw] = (f32x4){0.f,0.f,0.f,0.f};
    #pragma unroll
    for (int oo = 0; oo < 4; ++oo) {
        int o = wv*4 + oo;
        s16x8 fa[2], fb[2];
        #pragma unroll
        for (int mu = 0; mu < 2; ++mu) {
            int u = mu*16 + l15; if (u > 24) u = 24;
            fa[mu] = *(const s16x8*)(emb + ((((u*32 + o)*ATC + lhi*8)*2) ^ ((u&7)<<4)));
        }
        #pragma unroll
        for (int nw = 0; nw < 2; ++nw) {
            int w = nw*16 + l15; if (w > 24) w = 24;
            fb[nw] = *(const s16x8*)(emb + ((((w*32 + 16 + o)*ATC + lhi*8)*2) ^ ((w&7)<<4)));
        }
        #pragma unroll
        for (int mu = 0; mu < 2; ++mu)
            #pragma unroll
            for (int nw = 0; nw < 2; ++nw)
                ag[mu][nw] = __builtin_amdgcn_mfma_f32_16x16x32_bf16(fa[mu], fb[nw], ag[mu][nw], 0,0,0);
    }
    #pragma unroll
    for (int mu = 0; mu < 2; ++mu)
        #pragma unroll
        for (int nw = 0; nw < 2; ++nw)
            #pragma unroll
            for (int r = 0; r < 4; ++r) {
                int u = mu*16 + lhi*4 + r;
                int w = nw*16 + l15;
                if (u < 25 && w < 25)
                    atomicAdd(&gram[u*25 + w], ag[mu][nw][r]);
            }
    __syncthreads();
    for (int e = tid; e < 625; e += 256)
        Mpart[(long)b*625 + e] = gram[e];
}

// ---- softmax over summed partials + A+PA -> pre-padded bf16 attnbf ----
__global__ void k_softmax(const float* __restrict__ A, const float* __restrict__ PA,
                          const float* __restrict__ Mpart,
                          unsigned short* __restrict__ attnbf) {
    int b = blockIdx.x;          // = i*NB + n
    int i = b / NB, n = b % NB;
    int w = threadIdx.x;         // v (0..31)
    unsigned short* row = attnbf + (((long)n*NSUB + i)*32 + w)*40;
    if (w >= 25) {
        if (w < 32) {
            #pragma unroll
            for (int u = 0; u < 40; ++u) row[u] = 0;
        }
        return;
    }
    const float* Mp = Mpart + (long)b * ATCN * 625;
    const float scale = 1.0f / (float)(ICB * TF);
    float col[25];
    float mx = -1e30f;
    #pragma unroll
    for (int u = 0; u < 25; ++u) {
        float s = 0.f;
        #pragma unroll
        for (int tc = 0; tc < ATCN; ++tc)
            s += Mp[tc*625 + u*25 + w];
        col[u] = s * scale;
        mx = fmaxf(mx, col[u]);
    }
    float s = 0.f;
    #pragma unroll
    for (int u = 0; u < 25; ++u) { col[u] = __expf(col[u] - mx); s += col[u]; }
    float inv = 1.0f / s;
    #pragma unroll
    for (int u = 0; u < 25; ++u)
        row[u] = f2bf(col[u]*inv + A[i*625 + u*25 + w] + PA[i*625 + u*25 + w]);
    #pragma unroll
    for (int u = 25; u < 40; ++u) row[u] = 0;
}

// ---- fused y: swapped GEMM1 + bpermute z-transpose + GEMM2; plain stats stores ----
__global__ __launch_bounds__(256) void k_yz(
    const unsigned short* __restrict__ xbc, const unsigned short* __restrict__ attnbf,
    const unsigned short* __restrict__ wdcat, const float* __restrict__ bd,
    unsigned short* __restrict__ ybuf, float* __restrict__ pstats)
{
    __shared__ __align__(16) unsigned short attnT[NSUB*32*40];   // 15360 B
    __shared__ float ss[64], sq[64];

    int b = blockIdx.x;
    int n = b / 75, tq = b % 75;
    int tid = threadIdx.x;
    int wv = tid >> 6, l = tid & 63, l15 = l & 15, lhi = l >> 4;

    if (tid < 64) { ss[tid] = 0.f; sq[tid] = 0.f; }
    {
        const uint4* srcp = (const uint4*)(attnbf + (long)n * (NSUB*32*40));
        uint4* dstp = (uint4*)attnT;
        for (int e = tid; e < 480; e += 256) dstp[e] = srcp[e];
    }
    __syncthreads();

    int tg = tq*4 + wv;
    const unsigned short* xr = xbc + (long)n*CTVsz + tg*25;
    s16x8 afx[4];
    #pragma unroll
    for (int mf = 0; mf < 4; ++mf)
        afx[mf] = *(const s16x8*)(xr + (long)(mf*16 + l15)*TVsz + lhi*8);

    f32x4 acc2[4][2];
    #pragma unroll
    for (int mf = 0; mf < 4; ++mf)
        #pragma unroll
        for (int nf = 0; nf < 2; ++nf)
            acc2[mf][nf] = (f32x4){0.f,0.f,0.f,0.f};

    int srcA4 = (l15 + 32*(lhi & 1)) << 2;
    int srcB4 = srcA4 + 64;
    bool hsel = (lhi & 2) != 0;

    const f32x4 zero4 = (f32x4){0.f,0.f,0.f,0.f};
    for (int i = 0; i < NSUB; ++i) {
        s16x8 bfa0 = *(const s16x8*)(attnT + (i*32 + l15)*40 + lhi*8);
        s16x8 bfa1 = *(const s16x8*)(attnT + (i*32 + 16 + l15)*40 + lhi*8);
        f32x4 zacc[4][2];
        #pragma unroll
        for (int mf = 0; mf < 4; ++mf) {
            zacc[mf][0] = __builtin_amdgcn_mfma_f32_16x16x32_bf16(afx[mf], bfa0, zero4, 0,0,0);
            zacc[mf][1] = __builtin_amdgcn_mfma_f32_16x16x32_bf16(afx[mf], bfa1, zero4, 0,0,0);
        }
        unsigned pk[4][2][2];
        #pragma unroll
        for (int mf = 0; mf < 4; ++mf)
            #pragma unroll
            for (int nf = 0; nf < 2; ++nf) {
                pk[mf][nf][0] = (unsigned)f2bf(zacc[mf][nf][0]) | ((unsigned)f2bf(zacc[mf][nf][1]) << 16);
                pk[mf][nf][1] = (unsigned)f2bf(zacc[mf][nf][2]) | ((unsigned)f2bf(zacc[mf][nf][3]) << 16);
            }
        #pragma unroll
        for (int kc = 0; kc < 2; ++kc) {
            s16x8 bz[2];
            #pragma unroll
            for (int nf = 0; nf < 2; ++nf) {
                unsigned dw0, dw1, dw2, dw3;
                {
                    unsigned a0 = (unsigned)__builtin_amdgcn_ds_bpermute(srcA4, (int)pk[kc*2+0][nf][0]);
                    unsigned a1 = (unsigned)__builtin_amdgcn_ds_bpermute(srcA4, (int)pk[kc*2+1][nf][0]);
                    unsigned b0 = (unsigned)__builtin_amdgcn_ds_bpermute(srcB4, (int)pk[kc*2+0][nf][0]);
                    unsigned b1 = (unsigned)__builtin_amdgcn_ds_bpermute(srcB4, (int)pk[kc*2+1][nf][0]);
                    dw0 = hsel ? a1 : a0;
                    dw2 = hsel ? b1 : b0;
                }
                {
                    unsigned a0 = (unsigned)__builtin_amdgcn_ds_bpermute(srcA4, (int)pk[kc*2+0][nf][1]);
                    unsigned a1 = (unsigned)__builtin_amdgcn_ds_bpermute(srcA4, (int)pk[kc*2+1][nf][1]);
                    unsigned b0 = (unsigned)__builtin_amdgcn_ds_bpermute(srcB4, (int)pk[kc*2+0][nf][1]);
                    unsigned b1 = (unsigned)__builtin_amdgcn_ds_bpermute(srcB4, (int)pk[kc*2+1][nf][1]);
                    dw1 = hsel ? a1 : a0;
                    dw3 = hsel ? b1 : b0;
                }
                union { s16x8 v; unsigned u[4]; } tmp;
                tmp.u[0] = dw0; tmp.u[1] = dw1; tmp.u[2] = dw2; tmp.u[3] = dw3;
                bz[nf] = tmp.v;
            }
            #pragma unroll
            for (int mf2 = 0; mf2 < 4; ++mf2) {
                s16x8 afw = *(const s16x8*)(wdcat + ((i*CH + mf2*16 + l15)*CH + kc*32 + lhi*8));
                acc2[mf2][0] = __builtin_amdgcn_mfma_f32_16x16x32_bf16(afw, bz[0], acc2[mf2][0], 0,0,0);
                acc2[mf2][1] = __builtin_amdgcn_mfma_f32_16x16x32_bf16(afw, bz[1], acc2[mf2][1], 0,0,0);
            }
        }
    }

    #pragma unroll
    for (int mf = 0; mf < 4; ++mf) {
        #pragma unroll
        for (int r = 0; r < 4; ++r) {
            int o = mf*16 + lhi*4 + r;
            float bds = bd[o] + bd[CH + o] + bd[2*CH + o];
            float p = 0.f, q = 0.f;
            #pragma unroll
            for (int nf = 0; nf < 2; ++nf) {
                int v = nf*16 + l15;
                if (v < VJ) {
                    float val = acc2[mf][nf][r] + bds;
                    ybuf[((long)n*CH + o)*TVsz + tg*25 + v] = f2bf(val);
                    p += val; q += val*val;
                }
            }
            p += __shfl_xor(p, 1, 64); q += __shfl_xor(q, 1, 64);
            p += __shfl_xor(p, 2, 64); q += __shfl_xor(q, 2, 64);
            p += __shfl_xor(p, 4, 64); q += __shfl_xor(q, 4, 64);
            p += __shfl_xor(p, 8, 64); q += __shfl_xor(q, 8, 64);
            if (l15 == 0) { atomicAdd(&ss[o], p); atomicAdd(&sq[o], q); }
        }
    }
    __syncthreads();
    if (tid < 64) {
        pstats[(long)b*128 + tid]      = ss[tid];
        pstats[(long)b*128 + 64 + tid] = sq[tid];
    }
}

// ---- reduce per-block partial stats -> stats (plain stores) ----
__global__ __launch_bounds__(256) void k_red(const float* __restrict__ pstats, int cnt,
                                             float* __restrict__ s1, float* __restrict__ s2) {
    int col = blockIdx.x;   // 0..127: 0-63 sum, 64-127 sumsq
    int tid = threadIdx.x;
    float s = 0.f;
    for (int e = tid; e < cnt; e += 256)
        s += pstats[(long)e*128 + col];
    #pragma unroll
    for (int off = 32; off; off >>= 1) s += __shfl_down(s, off, 64);
    __shared__ float rs[4];
    int wid = tid >> 6, lane = tid & 63;
    if (lane == 0) rs[wid] = s;
    __syncthreads();
    if (tid == 0) {
        float t = rs[0]+rs[1]+rs[2]+rs[3];
        if (col < 64) s1[col] = t; else s2[col-64] = t;
    }
}

// ------ y = relu(bn1(y)+x) -> bf16, t-major [n][v][t][c]; residual from xbc bf16 ----
__global__ __launch_bounds__(256) void k_bn1t(
    const unsigned short* __restrict__ xc, const float* __restrict__ g1, const float* __restrict__ b1,
    const float* __restrict__ s1, const float* __restrict__ s2,
    const unsigned short* __restrict__ yb, unsigned short* __restrict__ ybt)
{
    __shared__ unsigned short ls[64*66];
    int b = blockIdx.x;
    int n = b / 118, tile = b % 118;
    int tv0 = tile * 64;
    const float invN = 1.0f / (float)PCCOUNT;
    int tid = threadIdx.x;

    for (int e = tid; e < 1024; e += 256) {
        int c = e >> 4, t4 = (e & 15) * 4;
        int tv = tv0 + t4;
        if (tv < TVsz) {
            long gbase = (long)n*CTVsz + (long)c*TVsz;
            float m  = s1[c] * invN;
            float vr = s2[c] * invN - m*m;
            float sc = rsqrtf(vr + EPSB) * g1[c];
            float bc = b1[c];
            uint2 yv = *(const uint2*)(yb + gbase + tv);
            uint2 xv = *(const uint2*)(xc + gbase + tv);
            ls[(t4+0)*66 + c] = f2bf(fmaxf((bf2f(yv.x & 0xffffu) - m)*sc + bc + bf2f(xv.x & 0xffffu), 0.f));
            ls[(t4+1)*66 + c] = f2bf(fmaxf((bf2f(yv.x >> 16)     - m)*sc + bc + bf2f(xv.x >> 16),     0.f));
            ls[(t4+2)*66 + c] = f2bf(fmaxf((bf2f(yv.y & 0xffffu) - m)*sc + bc + bf2f(xv.y & 0xffffu), 0.f));
            ls[(t4+3)*66 + c] = f2bf(fmaxf((bf2f(yv.y >> 16)     - m)*sc + bc + bf2f(xv.y >> 16),     0.f));
        }
    }
    __syncthreads();
    for (int e = tid; e < 1024; e += 256) {
        int tvl = e >> 4, c4 = (e & 15) * 4;
        int tv = tv0 + tvl;
        if (tv < TVsz) {
            int v = tv % 25, t = tv / 25;
            unsigned int lo = *(const unsigned int*)&ls[tvl*66 + c4];
            unsigned int hi = *(const unsigned int*)&ls[tvl*66 + c4 + 2];
            *(uint2*)&ybt[(((long)n*VJ + v)*TF + t)*CH + c4] = make_uint2(lo, hi);
        }
    }
}

// ------- temporal conv: block=(n,v), full t, 4 waves x acc[4][5]; plain stats ----
#define TCROWS 316

__global__ __launch_bounds__(256) void k_tconv(
    const unsigned short* __restrict__ ybt, const unsigned short* __restrict__ awT,
    const float* __restrict__ bt, unsigned short* __restrict__ ycb,
    float* __restrict__ pstats2)
{
    __shared__ __align__(16) char ys[TCROWS*128];   // 40.4 KB, XOR-swizzled
    __shared__ float ss[64], sq[64];
    int b = blockIdx.x;
    int n = b / VJ, v = b % VJ;
    int tid = threadIdx.x;
    int wv = tid >> 6, l = tid & 63, l15 = l & 15, lhi = l >> 4;
    if (tid < 64) { ss[tid] = 0.f; sq[tid] = 0.f; }

    const char* src = (const char*)(ybt + (((long)n*VJ + v)*TF)*CH);
    for (int qq = tid; qq < TCROWS*8; qq += 256) {
        int row = qq >> 3;
        int cb  = (qq & 7) << 4;
        int tg = row - 4;
        uint4 val = make_uint4(0u,0u,0u,0u);
        if (tg >= 0 && tg < TF)
            val = *(const uint4*)(src + (long)tg*128 + cb);
        *(uint4*)(ys + row*128 + (cb ^ ((row & 7) << 4))) = val;
    }
    __syncthreads();

    int wt0 = wv * 75;
    const short* aw = (const short*)awT;

    f32x4 acc[4][5];
    #pragma unroll
    for (int mf = 0; mf < 4; ++mf)
        #pragma unroll
        for (int nf = 0; nf < 5; ++nf)
            acc[mf][nf] = (f32x4){0.f,0.f,0.f,0.f};

    for (int tap = 0; tap < KW; ++tap) {
        #pragma unroll
        for (int kc = 0; kc < 2; ++kc) {
            s16x8 af[4], bfr[5];
            #pragma unroll
            for (int mf = 0; mf < 4; ++mf)
                af[mf] = *(const s16x8*)(aw + ((tap*CH + mf*16 + l15)*CH + kc*32 + lhi*8));
            #pragma unroll
            for (int nf = 0; nf < 5; ++nf) {
                int rloc = wt0 + nf*16 + l15 + tap;
                int cb = (kc*64 + lhi*16) ^ ((rloc & 7) << 4);
                bfr[nf] = *(const s16x8*)(ys + rloc*128 + cb);
            }
            #pragma unroll
            for (int mf = 0; mf < 4; ++mf)
                #pragma unroll
                for (int nf = 0; nf < 5; ++nf)
                    acc[mf][nf] = __builtin_amdgcn_mfma_f32_16x16x32_bf16(
                        af[mf], bfr[nf], acc[mf][nf], 0, 0, 0);
        }
    }

    #pragma unroll
    for (int mf = 0; mf < 4; ++mf) {
        #pragma unroll
        for (int r = 0; r < 4; ++r) {
            int o = mf*16 + lhi*4 + r;
            float bo = bt[o];
            float p = 0.f, q = 0.f;
            #pragma unroll
            for (int nf = 0; nf < 5; ++nf) {
                int tle = nf*16 + l15;
                if (tle < 75) {
                    float val = acc[mf][nf][r] + bo;
                    ycb[(((long)n*CH + o)*VJ + v)*TF + wt0 + tle] = f2bf(val);
                    p += val; q += val*val;
                }
            }
            p += __shfl_xor(p, 1, 64); q += __shfl_xor(q, 1, 64);
            p += __shfl_xor(p, 2, 64); q += __shfl_xor(q, 2, 64);
            p += __shfl_xor(p, 4, 64); q += __shfl_xor(q, 4, 64);
            p += __shfl_xor(p, 8, 64); q += __shfl_xor(q, 8, 64);
            if (l15 == 0) { atomicAdd(&ss[o], p); atomicAdd(&sq[o], q); }
        }
    }
    __syncthreads();
    if (tid < 64) {
        pstats2[(long)b*128 + tid]      = ss[tid];
        pstats2[(long)b*128 + 64 + tid] = sq[tid];
    }
}

// ------- out = relu(bn2(yc)+x): block=(n,c), LDS v<->t transpose; x from xbc bf16 ----
__global__ __launch_bounds__(256) void k_out(
    const unsigned short* __restrict__ xc, const float* __restrict__ g2, const float* __restrict__ b2,
    const float* __restrict__ s1, const float* __restrict__ s2,
    const unsigned short* __restrict__ ycb, float* __restrict__ out)
{
    __shared__ float ls[VJ*305];
    const float invN = 1.0f / (float)PCCOUNT;
    int b = blockIdx.x;
    int n = b >> 6, c = b & 63;
    int tid = threadIdx.x;

    float m  = s1[c] * invN;
    float vr = s2[c] * invN - m*m;
    float rs = rsqrtf(vr + EPSB) * g2[c];
    float bc = b2[c];

    const uint2* yc = (const uint2*)(ycb + ((long)n*CH + c)*TVsz);
    for (int e = tid; e < TVsz/4; e += 256) {
        uint2 d = yc[e];
        int base = e*4;
        int v = base / TF, t = base % TF;
        float* lp = &ls[v*305 + t];
        lp[0] = (bf2f(d.x & 0xffffu) - m)*rs + bc;
        lp[1] = (bf2f(d.x >> 16)     - m)*rs + bc;
        lp[2] = (bf2f(d.y & 0xffffu) - m)*rs + bc;
        lp[3] = (bf2f(d.y >> 16)     - m)*rs + bc;
    }
    __syncthreads();

    long gbase = ((long)n*CH + c)*TVsz;
    const uint2* xp = (const uint2*)(xc + gbase);
    for (int e = tid; e < TVsz/4; e += 256) {
        int tv = e*4;
        uint2 xv = xp[e];
        float4 ov;
        { int v = (tv+0) % 25, t = (tv+0) / 25; ov.x = fmaxf(ls[v*305 + t] + bf2f(xv.x & 0xffffu), 0.f); }
        { int v = (tv+1) % 25, t = (tv+1) / 25; ov.y = fmaxf(ls[v*305 + t] + bf2f(xv.x >> 16),     0.f); }
        { int v = (tv+2) % 25, t = (tv+2) / 25; ov.z = fmaxf(ls[v*305 + t] + bf2f(xv.y & 0xffffu), 0.f); }
        { int v = (tv+3) % 25, t = (tv+3) / 25; ov.w = fmaxf(ls[v*305 + t] + bf2f(xv.y >> 16),     0.f); }
        *(float4*)(out + gbase + tv) = ov;
    }
}

extern "C" void kernel_launch(void* const* d_in, const int* in_sizes, int n_in,
                              void* d_out, int out_size, void* d_ws, size_t ws_size,
                              hipStream_t stream) {
    const float* x  = (const float*)d_in[0];
    const float* A  = (const float*)d_in[1];
    const float* PA = (const float*)d_in[2];
    const float* Wa = (const float*)d_in[3];
    const float* ba = (const float*)d_in[4];
    const float* Wb = (const float*)d_in[5];
    const float* bb = (const float*)d_in[6];
    const float* Wd = (const float*)d_in[7];
    const float* bd = (const float*)d_in[8];
    const float* g1 = (const float*)d_in[9];
    const float* b1 = (const float*)d_in[10];
    const float* Wt = (const float*)d_in[11];
    const float* bt = (const float*)d_in[12];
    const float* g2 = (const float*)d_in[13];
    const float* b2 = (const float*)d_in[14];

    float* ws    = (float*)d_ws;
    float* stats = ws + 60000;                                 // [60000, 60256)
    unsigned short* attnbf = (unsigned short*)(ws + 60256);    // -> 121696
    unsigned short* wdcat  = (unsigned short*)(ws + 121696);   // -> 127840
    unsigned short* wcat   = (unsigned short*)(ws + 127840);   // -> 130912
    float* biascat = ws + 130912;                              // -> 131008
    unsigned short* awT    = (unsigned short*)(ws + 131008);   // -> 149440
    unsigned short* xbt    = (unsigned short*)(ws + 149440);   // 15.36M sh -> 7829440
    unsigned short* xbc    = (unsigned short*)(ws + 7829440);  // 15.36M sh -> 15509440
    unsigned short* ybuf   = (unsigned short*)(ws + 15509440); // [n][o][tv] -> 23189440
    float* pstats  = ws + 23189440;                            // 2400*128 -> 23496640
    float* pstats2 = ws + 23496640;                            // 800*128  -> 23599040
    float* Mpart   = ws + 23599040;                            // 960*625  -> 24199040
    // overlays: xbc stays LIVE through the tail (bf16 residual for bn1t/out).
    unsigned short* ybt = xbt;    // xbt dead after k_attn
    unsigned short* ycb = ybuf;   // ybuf dead after k_bn1t

    k_prep<<<217, 256, 0, stream>>>(Wt, Wd, Wa, ba, Wb, bb, awT, wdcat, wcat, biascat);
    k_xt<<<NB*118, 256, 0, stream>>>(x, xbt, xbc);
    k_attn<<<NSUB*NB*ATCN, 256, 0, stream>>>(xbt, wcat, biascat, Mpart);
    k_softmax<<<NSUB*NB, 32, 0, stream>>>(A, PA, Mpart, attnbf);
    k_yz<<<YZBLK, 256, 0, stream>>>(xbc, attnbf, wdcat, bd, ybuf, pstats);
    k_red<<<128, 256, 0, stream>>>(pstats, YZBLK, stats, stats + 64);
    k_bn1t<<<NB*118, 256, 0, stream>>>(xbc, g1, b1, stats, stats + 64, ybuf, ybt);
    k_tconv<<<TCBLK, 256, 0, stream>>>(ybt, awT, bt, ycb, pstats2);
    k_red<<<128, 256, 0, stream>>>(pstats2, TCBLK, stats + 128, stats + 192);
    k_out<<<NB*CH, 256, 0, stream>>>(xbc, g2, b2, stats + 128, stats + 192, ycb, (float*)d_out);
}